// Round 1
// baseline (3786.908 us; speedup 1.0000x reference)
//
#include <hip/hip_runtime.h>
#include <cstdint>
#include <cstddef>

#define EPSF 1e-5f

// Dims (fixed by the problem)
#define BB 8
#define CC 128
#define HH 64
#define TT 512
#define HW (HH*TT)          // 32768
#define NPIX (BB*HH*TT)     // 262144

__device__ __forceinline__ float sigf(float x) { return 1.f / (1.f + expf(-x)); }
__device__ __forceinline__ float geluf(float z) { return 0.5f * z * (1.f + erff(z * 0.70710678118654752f)); }

// ---------------------------------------------------------------------------
// Pointwise conv (1x1) + optional BN + activation.  out[b,o,h,t] = act(bn(sum_c in[b,c,h,t]*W[o,c]))
// Grid: (BB*HH)*(TT/64) = 4096 blocks, 256 threads. Each block: 64 t, all 128 o.
// ACT: 0=none, 1=relu, 2=sigmoid. FLIP: read input at t -> 511-t.
// ---------------------------------------------------------------------------
template<int CIN, int ACT, bool FLIP, bool BN>
__global__ __launch_bounds__(256) void pw_kernel(const float* __restrict__ in,
                                                 const float* __restrict__ W,
                                                 const float* __restrict__ bnp,
                                                 float* __restrict__ out)
{
    __shared__ float in_lds[64][64];
    __shared__ float w_lds[128][65];   // pad 65: o-stride 8 -> 8*65 % 32 = 8 -> conflict-free
    const int tid = threadIdx.x;
    const int bh = blockIdx.x >> 3, tt = blockIdx.x & 7;
    const int b = bh >> 6, h = bh & 63;
    const int t0 = tt << 6;

    float acc[8][4];
#pragma unroll
    for (int k = 0; k < 8; ++k)
#pragma unroll
        for (int j = 0; j < 4; ++j) acc[k][j] = 0.f;

    const int tl0 = (tid & 15) << 2;
    const int o0 = (tid >> 4) << 3;

    for (int c0 = 0; c0 < CIN; c0 += 64) {
#pragma unroll
        for (int i = 0; i < 16; ++i) {
            int idx = i * 256 + tid;
            int cl = idx >> 6, tl = idx & 63;
            int tsrc = t0 + tl;
            if (FLIP) tsrc = (TT - 1) - tsrc;
            in_lds[cl][tl] = in[((size_t)(b * CIN + c0 + cl) * HH + h) * TT + tsrc];
        }
#pragma unroll
        for (int i = 0; i < 32; ++i) {
            int idx = i * 256 + tid;
            int o = idx >> 6, cl = idx & 63;
            w_lds[o][cl] = W[o * CIN + c0 + cl];
        }
        __syncthreads();
#pragma unroll 2
        for (int c = 0; c < 64; ++c) {
            float4 x4 = *(const float4*)&in_lds[c][tl0];
#pragma unroll
            for (int k = 0; k < 8; ++k) {
                float wv = w_lds[o0 + k][c];
                acc[k][0] += x4.x * wv;
                acc[k][1] += x4.y * wv;
                acc[k][2] += x4.z * wv;
                acc[k][3] += x4.w * wv;
            }
        }
        __syncthreads();
    }

#pragma unroll
    for (int k = 0; k < 8; ++k) {
        int o = o0 + k;
        float sc = 1.f, sh = 0.f;
        if (BN) {
            float g = bnp[o], be = bnp[CC + o], m = bnp[2 * CC + o], v = bnp[3 * CC + o];
            sc = g * rsqrtf(v + EPSF);
            sh = be - m * sc;
        }
        float4 r;
        float vx[4];
#pragma unroll
        for (int j = 0; j < 4; ++j) {
            float v2 = acc[k][j] * sc + sh;
            if (ACT == 1) v2 = fmaxf(v2, 0.f);
            if (ACT == 2) v2 = sigf(v2);
            vx[j] = v2;
        }
        r.x = vx[0]; r.y = vx[1]; r.z = vx[2]; r.w = vx[3];
        *(float4*)&out[((size_t)(b * CC + o) * HH + h) * TT + t0 + tl0] = r;
    }
}

// ---------------------------------------------------------------------------
// Depthwise 5x5 'same' conv, two weight sets in one pass (branches a and b).
// Grid: BB*CC*(HH/16)*(TT/64) = 32768 blocks, 256 threads; 16x64 tile per block.
// ---------------------------------------------------------------------------
template<bool FLIP>
__global__ __launch_bounds__(256) void dw5x5_dual(const float* __restrict__ in,
                                                  const float* __restrict__ wa,
                                                  const float* __restrict__ wb,
                                                  float* __restrict__ oa,
                                                  float* __restrict__ ob)
{
    __shared__ float tile[20][68];
    __shared__ float wla[25], wlb[25];
    const int tid = threadIdx.x;
    const int bc = blockIdx.x >> 5;
    const int tl5 = blockIdx.x & 31;
    const int ht = tl5 >> 3, ttile = tl5 & 7;
    const int h0 = ht << 4, t0 = ttile << 6;
    const int c = bc & (CC - 1);
    const float* base = in + (size_t)bc * HW;

    if (tid < 25) { wla[tid] = wa[c * 25 + tid]; wlb[tid] = wb[c * 25 + tid]; }
    for (int idx = tid; idx < 20 * 68; idx += 256) {
        int hl = idx / 68, tl = idx % 68;
        int hh = h0 + hl - 2, t2 = t0 + tl - 2;
        float v = 0.f;
        if (hh >= 0 && hh < HH && t2 >= 0 && t2 < TT)
            v = base[hh * TT + (FLIP ? (TT - 1) - t2 : t2)];
        tile[hl][tl] = v;
    }
    __syncthreads();
#pragma unroll
    for (int rep = 0; rep < 4; ++rep) {
        int oi = rep * 256 + tid;
        int hl = oi >> 6, tl = oi & 63;
        float sa = 0.f, sb = 0.f;
#pragma unroll
        for (int di = 0; di < 5; ++di)
#pragma unroll
            for (int dj = 0; dj < 5; ++dj) {
                float x = tile[hl + di][tl + dj];
                sa += x * wla[di * 5 + dj];
                sb += x * wlb[di * 5 + dj];
            }
        size_t off = (size_t)bc * HW + (h0 + hl) * TT + t0 + tl;
        oa[off] = sa; ob[off] = sb;
    }
}

// ---------------------------------------------------------------------------
// Channel pooling: per (b,c) mean & max over HxT. Grid: 1024 blocks, 256 thr.
// ---------------------------------------------------------------------------
__global__ __launch_bounds__(256) void chan_pool(const float* __restrict__ in,
                                                 float* __restrict__ pavg,
                                                 float* __restrict__ pmax)
{
    __shared__ float ssum[256], smax[256];
    const int bc = blockIdx.x, tid = threadIdx.x;
    const float* p = in + (size_t)bc * HW;
    float s = 0.f, m = -3.4e38f;
    for (int i = tid; i < HW; i += 256) { float v = p[i]; s += v; m = fmaxf(m, v); }
    ssum[tid] = s; smax[tid] = m;
    __syncthreads();
    for (int w2 = 128; w2 > 0; w2 >>= 1) {
        if (tid < w2) { ssum[tid] += ssum[tid + w2]; smax[tid] = fmaxf(smax[tid], smax[tid + w2]); }
        __syncthreads();
    }
    if (tid == 0) { pavg[bc] = ssum[0] * (1.f / (float)HW); pmax[bc] = smax[0]; }
}

// ---------------------------------------------------------------------------
// Channel-attention MLP: a[b,c] = sigmoid(f(avg)+f(max)), f(u)=relu(u@w1.T)@w2.T
// One block, 256 threads. w1:[8][128], w2:[128][8].
// ---------------------------------------------------------------------------
__global__ __launch_bounds__(256) void chan_mlp(const float* __restrict__ pavg,
                                                const float* __restrict__ pmax,
                                                const float* __restrict__ w1,
                                                const float* __restrict__ w2,
                                                float* __restrict__ a)
{
    __shared__ float ua[8][128], um[8][128], hida[8][8], hidm[8][8];
    const int tid = threadIdx.x;
    for (int idx = tid; idx < 1024; idx += 256) {
        ua[idx >> 7][idx & 127] = pavg[idx];
        um[idx >> 7][idx & 127] = pmax[idx];
    }
    __syncthreads();
    if (tid < 128) {
        int b = tid >> 4, m = (tid >> 1) & 7, path = tid & 1;
        const float* u = path ? um[b] : ua[b];
        float acc = 0.f;
#pragma unroll
        for (int cc2 = 0; cc2 < 128; ++cc2) acc += u[cc2] * w1[m * 128 + cc2];
        acc = fmaxf(acc, 0.f);
        if (path) hidm[b][m] = acc; else hida[b][m] = acc;
    }
    __syncthreads();
    for (int idx = tid; idx < 1024; idx += 256) {
        int b = idx >> 7, cc2 = idx & 127;
        float acc = 0.f;
#pragma unroll
        for (int m = 0; m < 8; ++m) acc += (hida[b][m] + hidm[b][m]) * w2[cc2 * 8 + m];
        a[idx] = sigf(acc);
    }
}

// ---------------------------------------------------------------------------
// cb = b1*b1*a[b,c] followed by depthwise 1x3 'same' conv along t.
// Grid: 32768 blocks, 256 thr; each thread: 4 consecutive t.
// ---------------------------------------------------------------------------
__global__ __launch_bounds__(256) void cb_dw1x3(const float* __restrict__ b1,
                                                const float* __restrict__ ach,
                                                const float* __restrict__ w,
                                                float* __restrict__ out)
{
    const int gid = blockIdx.x * 256 + threadIdx.x;
    const int t0 = (gid & 127) << 2;
    const int r = gid >> 7;
    const int h = r & 63;
    const int bc = r >> 6;
    const int c = bc & 127;
    const float* p = b1 + ((size_t)bc * HH + h) * TT;
    const float av = ach[bc];
    const float w0 = w[c * 3 + 0], w1v = w[c * 3 + 1], w2v = w[c * 3 + 2];
    float4 mid = *(const float4*)&p[t0];
    float cbm1 = 0.f, cb4 = 0.f;
    if (t0 > 0) { float l = p[t0 - 1]; cbm1 = l * l * av; }
    if (t0 + 4 < TT) { float rr = p[t0 + 4]; cb4 = rr * rr * av; }
    float c0 = mid.x * mid.x * av, c1 = mid.y * mid.y * av;
    float c2 = mid.z * mid.z * av, c3 = mid.w * mid.w * av;
    float4 o;
    o.x = cbm1 * w0 + c0 * w1v + c1 * w2v;
    o.y = c0 * w0 + c1 * w1v + c2 * w2v;
    o.z = c1 * w0 + c2 * w1v + c3 * w2v;
    o.w = c2 * w0 + c3 * w1v + cb4 * w2v;
    *(float4*)&out[((size_t)bc * HH + h) * TT + t0] = o;
}

// ---------------------------------------------------------------------------
// Spatial pooling: per-pixel mean & max over channels. Grid 1024x256.
// s layout: [b][2][h][t]
// ---------------------------------------------------------------------------
__global__ __launch_bounds__(256) void spat_pool(const float* __restrict__ in,
                                                 float* __restrict__ s)
{
    const int pix = blockIdx.x * 256 + threadIdx.x;
    const int t = pix & 511, h = (pix >> 9) & 63, b = pix >> 15;
    const float* p = in + ((size_t)b * CC * HH + h) * TT + t;
    float sum = 0.f, mx = -3.4e38f;
#pragma unroll 8
    for (int c = 0; c < CC; ++c) {
        float v = p[(size_t)c * HW];
        sum += v; mx = fmaxf(mx, v);
    }
    const int sp = h * TT + t;
    s[((size_t)b * 2) * HW + sp] = sum * (1.f / (float)CC);
    s[((size_t)b * 2 + 1) * HW + sp] = mx;
}

// ---------------------------------------------------------------------------
// 7x7 conv on the 2-channel pooled map + sigmoid. Grid 1024x256.
// ---------------------------------------------------------------------------
__global__ __launch_bounds__(256) void spat_conv(const float* __restrict__ s,
                                                 const float* __restrict__ w,
                                                 float* __restrict__ a)
{
    __shared__ float wl[98];
    const int tid = threadIdx.x;
    if (tid < 98) wl[tid] = w[tid];
    __syncthreads();
    const int pix = blockIdx.x * 256 + tid;
    const int t = pix & 511, h = (pix >> 9) & 63, b = pix >> 15;
    float acc = 0.f;
#pragma unroll
    for (int ch = 0; ch < 2; ++ch) {
        const float* sp = s + ((size_t)b * 2 + ch) * HW;
#pragma unroll
        for (int di = 0; di < 7; ++di) {
            int hh = h + di - 3;
            if (hh < 0 || hh >= HH) continue;
#pragma unroll
            for (int dj = 0; dj < 7; ++dj) {
                int t2 = t + dj - 3;
                if (t2 < 0 || t2 >= TT) continue;
                acc += sp[hh * TT + t2] * wl[ch * 49 + di * 7 + dj];
            }
        }
    }
    a[pix] = sigf(acc);
}

// ---------------------------------------------------------------------------
// SSM scan (input-independent): computes sc[c][t] for both blocks.
// Grid: 2 blocks x 512 threads. Chunked affine scan: M^64 by squaring,
// entry states stitched serially (8 steps), 8 waves re-scan chunks.
// ---------------------------------------------------------------------------
__global__ __launch_bounds__(512) void scan_kernel(const float* __restrict__ A1,
                                                   const float* __restrict__ B1,
                                                   const float* __restrict__ C1,
                                                   const float* __restrict__ A2,
                                                   const float* __restrict__ B2,
                                                   const float* __restrict__ C2,
                                                   float* __restrict__ sc1,
                                                   float* __restrict__ sc2,
                                                   float* __restrict__ Sws)
{
    const float* A = blockIdx.x ? A2 : A1;
    const float* Bv = blockIdx.x ? B2 : B1;
    const float* Cm = blockIdx.x ? C2 : C1;
    float* sc = blockIdx.x ? sc2 : sc1;
    float* Sg = Sws + (size_t)blockIdx.x * (TT * 32);

    __shared__ float M[32][33];   // M[j][i] = A[i][j]  (z_new = z@M)
    __shared__ float P[32][33];   // becomes M^64
    __shared__ float Q[32][33];
    __shared__ float L64[32];
    __shared__ float Eq[8][32];
    __shared__ float Cs[32][128];

    const int tid = threadIdx.x;
    const int wave = tid >> 6, lane = tid & 63;

    for (int idx = tid; idx < 1024; idx += 512) {
        int j = idx >> 5, i = idx & 31;
        float v = A[i * 32 + j];
        M[j][i] = v; P[j][i] = v;
    }
    for (int idx = tid; idx < 4096; idx += 512) Cs[idx >> 7][idx & 127] = Cm[idx];
    __syncthreads();

    // P = M^64 via 6 squarings
    for (int sq = 0; sq < 6; ++sq) {
        for (int idx = tid; idx < 1024; idx += 512) {
            int r = idx >> 5, c2 = idx & 31;
            float acc = 0.f;
#pragma unroll
            for (int k = 0; k < 32; ++k) acc += P[r][k] * P[k][c2];
            Q[r][c2] = acc;
        }
        __syncthreads();
        for (int idx = tid; idx < 1024; idx += 512) {
            int r = idx >> 5, c2 = idx & 31;
            P[r][c2] = Q[r][c2];
        }
        __syncthreads();
    }

    // wave 0: L64 (64 steps from zero state)
    if (wave == 0) {
        float bval = (lane < 32) ? Bv[lane] : 0.f;
        float z = 0.f;
        for (int r = 0; r < 64; ++r) {
            float zn = bval;
#pragma unroll
            for (int j = 0; j < 32; ++j) zn += __shfl(z, j, 64) * M[j][lane & 31];
            z = zn;
        }
        if (lane < 32) L64[lane] = z;
    }
    __syncthreads();

    // wave 0: entry states E_q
    if (wave == 0) {
        float e = 0.f;
        if (lane < 32) Eq[0][lane] = 0.f;
        for (int q = 1; q < 8; ++q) {
            float en = (lane < 32) ? L64[lane] : 0.f;
#pragma unroll
            for (int j = 0; j < 32; ++j) en += __shfl(e, j, 64) * P[j][lane & 31];
            e = en;
            if (lane < 32) Eq[q][lane] = e;
        }
    }
    __syncthreads();

    // all 8 waves: re-scan chunks, write S to global scratch
    {
        float bval = (lane < 32) ? Bv[lane] : 0.f;
        float z = (lane < 32) ? Eq[wave][lane] : 0.f;
        for (int r = 0; r < 64; ++r) {
            float zn = bval;
#pragma unroll
            for (int j = 0; j < 32; ++j) zn += __shfl(z, j, 64) * M[j][lane & 31];
            z = zn;
            if (lane < 32) Sg[(wave * 64 + r) * 32 + lane] = z;
        }
    }
    __syncthreads();

    // sc[c][t] = S[t] . Cm[:,c]
    {
        float sreg[32];
#pragma unroll
        for (int j = 0; j < 32; ++j) sreg[j] = Sg[tid * 32 + j];
        for (int c = 0; c < 128; ++c) {
            float acc = 0.f;
#pragma unroll
            for (int j = 0; j < 32; ++j) acc += sreg[j] * Cs[j][c];
            sc[c * TT + tid] = acc;
        }
    }
}

// ---------------------------------------------------------------------------
// SSM apply + LayerNorm + multiply by spatial branch.
// out[b,c,h,t] = LN_c(cb2 + gelu(sc[c,t] + cb2*D[c])) * sigmoid(b2^2 * aspat)
// Grid 1024x256; thread owns one (b,h,t) column of 128 channels in registers.
// ---------------------------------------------------------------------------
__global__ __launch_bounds__(256) void ssm_apply(const float* __restrict__ cb2,
                                                 const float* __restrict__ b2,
                                                 const float* __restrict__ aspat,
                                                 const float* __restrict__ sc,
                                                 const float* __restrict__ Dv,
                                                 const float* __restrict__ ln,
                                                 float* __restrict__ out)
{
    const int pix = blockIdx.x * 256 + threadIdx.x;
    const int t = pix & 511, h = (pix >> 9) & 63, b = pix >> 15;
    const size_t base = ((size_t)b * CC * HH + h) * TT + t;
    float col[128];
    float sum = 0.f, sq = 0.f;
#pragma unroll
    for (int c = 0; c < 128; ++c) {
        float x = cb2[base + (size_t)c * HW];
        float z = sc[c * TT + t] + x * Dv[c];
        float o = x + geluf(z);
        col[c] = o;
        sum += o; sq += o * o;
    }
    float mu = sum * (1.f / 128.f);
    float var = sq * (1.f / 128.f) - mu * mu;
    float rstd = rsqrtf(var + EPSF);
    float asv = aspat[pix];
#pragma unroll
    for (int c = 0; c < 128; ++c) {
        float val = (col[c] - mu) * rstd * ln[c] + ln[128 + c];
        float bv = b2[base + (size_t)c * HW];
        float sb = sigf(bv * bv * asv);
        out[base + (size_t)c * HW] = val * sb;
    }
}

// ---------------------------------------------------------------------------
// Host-side launch
// ---------------------------------------------------------------------------
extern "C" void kernel_launch(void* const* d_in, const int* in_sizes, int n_in,
                              void* d_out, int out_size, void* d_ws, size_t ws_size,
                              hipStream_t stream)
{
    (void)in_sizes; (void)n_in; (void)out_size; (void)ws_size;

    auto pf = [&](int i) { return (const float*)d_in[i]; };

    const float* x = pf(0);
    const float* w_in = pf(1);
    const float* w_out = pf(2);
    const float* bn_out = pf(3);

    float* W = (float*)d_ws;
    const size_t NT = (size_t)BB * CC * HH * TT;      // 33554432
    float* S0 = W;
    float* S1 = W + NT;
    float* sc1 = W + 2 * NT;
    float* sc2 = sc1 + CC * TT;
    float* Sws = sc2 + CC * TT;                       // 2*512*32
    float* pavg = Sws + 2 * TT * 32;
    float* pmax = pavg + BB * CC;
    float* achan = pmax + BB * CC;
    float* sspat = achan + BB * CC;                   // 8*2*32768
    float* aspat = sspat + (size_t)BB * 2 * HW;       // 262144
    float* OUT = (float*)d_out;

    const dim3 blk(256);
    const int PW_GRID = (BB * HH) * (TT / 64);        // 4096
    const int DW_GRID = BB * CC * (HH / 16) * (TT / 64); // 32768
    const int PIX_GRID = NPIX / 256;                  // 1024
    const int D1_GRID = (BB * CC * HH * (TT / 4)) / 256; // 32768

    // SSM tables for both blocks (input independent)
    scan_kernel<<<2, 512, 0, stream>>>(pf(16), pf(17), pf(18), pf(33), pf(34), pf(35), sc1, sc2, Sws);

    // stem: x = pw(x, w_in)
    pw_kernel<64, 0, false, false><<<PW_GRID, blk, 0, stream>>>(x, w_in, nullptr, S0);

    auto run_block = [&](int pb, const float* I, float* Iw, float* U, float* V,
                         bool flip, const float* scp) {
        // I==Iw (const alias). dw5x5 both branches: I -> U (Da), V (Db)
        if (flip)
            dw5x5_dual<true><<<DW_GRID, blk, 0, stream>>>(I, pf(pb + 0), pf(pb + 3), U, V);
        else
            dw5x5_dual<false><<<DW_GRID, blk, 0, stream>>>(I, pf(pb + 0), pf(pb + 3), U, V);
        // b1 = relu(bn(pw(Da))) -> Iw ; b2 = relu(bn(pw(Db))) -> U
        pw_kernel<128, 1, false, true><<<PW_GRID, blk, 0, stream>>>(U, pf(pb + 1), pf(pb + 2), Iw);
        pw_kernel<128, 1, false, true><<<PW_GRID, blk, 0, stream>>>(V, pf(pb + 4), pf(pb + 5), U);
        // channel attention on b1
        chan_pool<<<BB * CC, blk, 0, stream>>>(Iw, pavg, pmax);
        chan_mlp<<<1, blk, 0, stream>>>(pavg, pmax, pf(pb + 6), pf(pb + 7), achan);
        // cb chain: (b1^2*a) -> dw1x3 -> V ; pw+bn+sigmoid -> Iw (cb2)
        cb_dw1x3<<<D1_GRID, blk, 0, stream>>>(Iw, achan, pf(pb + 9), V);
        pw_kernel<128, 2, false, true><<<PW_GRID, blk, 0, stream>>>(V, pf(pb + 10), pf(pb + 11), Iw);
        // spatial attention on b2 (U)
        spat_pool<<<PIX_GRID, blk, 0, stream>>>(U, sspat);
        spat_conv<<<PIX_GRID, blk, 0, stream>>>(sspat, pf(pb + 8), aspat);
        // ssm apply + LN + * sb  -> V
        ssm_apply<<<PIX_GRID, blk, 0, stream>>>(Iw, U, aspat, scp, pf(pb + 15), pf(pb + 16), V);
        // block output now in V
    };

    // block 1: I=S0, U=S1, V=OUT -> out in OUT
    run_block(4, S0, S0, S1, OUT, false, sc1);
    // block 2 (reads flipped): I=OUT, U=S0, V=S1 -> out in S1 (flipped space)
    run_block(21, OUT, OUT, S0, S1, true, sc2);
    // final: relu(bn(pw(flip(S1), w_out))) -> d_out
    pw_kernel<128, 1, true, true><<<PW_GRID, blk, 0, stream>>>(S1, w_out, bn_out, OUT);
}

// Round 2
// 2926.556 us; speedup vs baseline: 1.2940x; 1.2940x over previous
//
#include <hip/hip_runtime.h>
#include <cstdint>
#include <cstddef>

#define EPSF 1e-5f

// Dims (fixed by the problem)
#define BB 8
#define CC 128
#define HH 64
#define TT 512
#define HW (HH*TT)          // 32768
#define NPIX (BB*HH*TT)     // 262144

__device__ __forceinline__ float sigf(float x) { return 1.f / (1.f + expf(-x)); }
__device__ __forceinline__ float geluf(float z) { return 0.5f * z * (1.f + erff(z * 0.70710678118654752f)); }

// ---------------------------------------------------------------------------
// Pointwise conv (1x1) + optional BN + activation.  out[b,o,h,t] = act(bn(sum_c in[b,c,h,t]*W[o,c]))
// Grid: (BB*HH)*(TT/64) = 4096 blocks, 256 threads. Each block: 64 t, all 128 o.
// ACT: 0=none, 1=relu, 2=sigmoid. FLIP: read input at t -> 511-t.
// ---------------------------------------------------------------------------
template<int CIN, int ACT, bool FLIP, bool BN>
__global__ __launch_bounds__(256) void pw_kernel(const float* __restrict__ in,
                                                 const float* __restrict__ W,
                                                 const float* __restrict__ bnp,
                                                 float* __restrict__ out)
{
    __shared__ float in_lds[64][64];
    __shared__ float w_lds[128][65];   // pad 65: o-stride 8 -> 8*65 % 32 = 8 -> conflict-free
    const int tid = threadIdx.x;
    const int bh = blockIdx.x >> 3, tt = blockIdx.x & 7;
    const int b = bh >> 6, h = bh & 63;
    const int t0 = tt << 6;

    float acc[8][4];
#pragma unroll
    for (int k = 0; k < 8; ++k)
#pragma unroll
        for (int j = 0; j < 4; ++j) acc[k][j] = 0.f;

    const int tl0 = (tid & 15) << 2;
    const int o0 = (tid >> 4) << 3;

    for (int c0 = 0; c0 < CIN; c0 += 64) {
#pragma unroll
        for (int i = 0; i < 16; ++i) {
            int idx = i * 256 + tid;
            int cl = idx >> 6, tl = idx & 63;
            int tsrc = t0 + tl;
            if (FLIP) tsrc = (TT - 1) - tsrc;
            in_lds[cl][tl] = in[((size_t)(b * CIN + c0 + cl) * HH + h) * TT + tsrc];
        }
#pragma unroll
        for (int i = 0; i < 32; ++i) {
            int idx = i * 256 + tid;
            int o = idx >> 6, cl = idx & 63;
            w_lds[o][cl] = W[o * CIN + c0 + cl];
        }
        __syncthreads();
#pragma unroll 2
        for (int c = 0; c < 64; ++c) {
            float4 x4 = *(const float4*)&in_lds[c][tl0];
#pragma unroll
            for (int k = 0; k < 8; ++k) {
                float wv = w_lds[o0 + k][c];
                acc[k][0] += x4.x * wv;
                acc[k][1] += x4.y * wv;
                acc[k][2] += x4.z * wv;
                acc[k][3] += x4.w * wv;
            }
        }
        __syncthreads();
    }

#pragma unroll
    for (int k = 0; k < 8; ++k) {
        int o = o0 + k;
        float sc = 1.f, sh = 0.f;
        if (BN) {
            float g = bnp[o], be = bnp[CC + o], m = bnp[2 * CC + o], v = bnp[3 * CC + o];
            sc = g * rsqrtf(v + EPSF);
            sh = be - m * sc;
        }
        float4 r;
        float vx[4];
#pragma unroll
        for (int j = 0; j < 4; ++j) {
            float v2 = acc[k][j] * sc + sh;
            if (ACT == 1) v2 = fmaxf(v2, 0.f);
            if (ACT == 2) v2 = sigf(v2);
            vx[j] = v2;
        }
        r.x = vx[0]; r.y = vx[1]; r.z = vx[2]; r.w = vx[3];
        *(float4*)&out[((size_t)(b * CC + o) * HH + h) * TT + t0 + tl0] = r;
    }
}

// ---------------------------------------------------------------------------
// Depthwise 5x5 'same' conv, two weight sets in one pass (branches a and b).
// Grid: BB*CC*(HH/16)*(TT/64) = 32768 blocks, 256 threads; 16x64 tile per block.
// ---------------------------------------------------------------------------
template<bool FLIP>
__global__ __launch_bounds__(256) void dw5x5_dual(const float* __restrict__ in,
                                                  const float* __restrict__ wa,
                                                  const float* __restrict__ wb,
                                                  float* __restrict__ oa,
                                                  float* __restrict__ ob)
{
    __shared__ float tile[20][68];
    __shared__ float wla[25], wlb[25];
    const int tid = threadIdx.x;
    const int bc = blockIdx.x >> 5;
    const int tl5 = blockIdx.x & 31;
    const int ht = tl5 >> 3, ttile = tl5 & 7;
    const int h0 = ht << 4, t0 = ttile << 6;
    const int c = bc & (CC - 1);
    const float* base = in + (size_t)bc * HW;

    if (tid < 25) { wla[tid] = wa[c * 25 + tid]; wlb[tid] = wb[c * 25 + tid]; }
    for (int idx = tid; idx < 20 * 68; idx += 256) {
        int hl = idx / 68, tl = idx % 68;
        int hh = h0 + hl - 2, t2 = t0 + tl - 2;
        float v = 0.f;
        if (hh >= 0 && hh < HH && t2 >= 0 && t2 < TT)
            v = base[hh * TT + (FLIP ? (TT - 1) - t2 : t2)];
        tile[hl][tl] = v;
    }
    __syncthreads();
#pragma unroll
    for (int rep = 0; rep < 4; ++rep) {
        int oi = rep * 256 + tid;
        int hl = oi >> 6, tl = oi & 63;
        float sa = 0.f, sb = 0.f;
#pragma unroll
        for (int di = 0; di < 5; ++di)
#pragma unroll
            for (int dj = 0; dj < 5; ++dj) {
                float x = tile[hl + di][tl + dj];
                sa += x * wla[di * 5 + dj];
                sb += x * wlb[di * 5 + dj];
            }
        size_t off = (size_t)bc * HW + (h0 + hl) * TT + t0 + tl;
        oa[off] = sa; ob[off] = sb;
    }
}

// ---------------------------------------------------------------------------
// Channel pooling: per (b,c) mean & max over HxT. Grid: 1024 blocks, 256 thr.
// ---------------------------------------------------------------------------
__global__ __launch_bounds__(256) void chan_pool(const float* __restrict__ in,
                                                 float* __restrict__ pavg,
                                                 float* __restrict__ pmax)
{
    __shared__ float ssum[256], smax[256];
    const int bc = blockIdx.x, tid = threadIdx.x;
    const float* p = in + (size_t)bc * HW;
    float s = 0.f, m = -3.4e38f;
    for (int i = tid; i < HW; i += 256) { float v = p[i]; s += v; m = fmaxf(m, v); }
    ssum[tid] = s; smax[tid] = m;
    __syncthreads();
    for (int w2 = 128; w2 > 0; w2 >>= 1) {
        if (tid < w2) { ssum[tid] += ssum[tid + w2]; smax[tid] = fmaxf(smax[tid], smax[tid + w2]); }
        __syncthreads();
    }
    if (tid == 0) { pavg[bc] = ssum[0] * (1.f / (float)HW); pmax[bc] = smax[0]; }
}

// ---------------------------------------------------------------------------
// Channel-attention MLP: a[b,c] = sigmoid(f(avg)+f(max)), f(u)=relu(u@w1.T)@w2.T
// One block, 256 threads. w1:[8][128], w2:[128][8].
// ---------------------------------------------------------------------------
__global__ __launch_bounds__(256) void chan_mlp(const float* __restrict__ pavg,
                                                const float* __restrict__ pmax,
                                                const float* __restrict__ w1,
                                                const float* __restrict__ w2,
                                                float* __restrict__ a)
{
    __shared__ float ua[8][128], um[8][128], hida[8][8], hidm[8][8];
    const int tid = threadIdx.x;
    for (int idx = tid; idx < 1024; idx += 256) {
        ua[idx >> 7][idx & 127] = pavg[idx];
        um[idx >> 7][idx & 127] = pmax[idx];
    }
    __syncthreads();
    if (tid < 128) {
        int b = tid >> 4, m = (tid >> 1) & 7, path = tid & 1;
        const float* u = path ? um[b] : ua[b];
        float acc = 0.f;
#pragma unroll
        for (int cc2 = 0; cc2 < 128; ++cc2) acc += u[cc2] * w1[m * 128 + cc2];
        acc = fmaxf(acc, 0.f);
        if (path) hidm[b][m] = acc; else hida[b][m] = acc;
    }
    __syncthreads();
    for (int idx = tid; idx < 1024; idx += 256) {
        int b = idx >> 7, cc2 = idx & 127;
        float acc = 0.f;
#pragma unroll
        for (int m = 0; m < 8; ++m) acc += (hida[b][m] + hidm[b][m]) * w2[cc2 * 8 + m];
        a[idx] = sigf(acc);
    }
}

// ---------------------------------------------------------------------------
// cb = b1*b1*a[b,c] followed by depthwise 1x3 'same' conv along t.
// Grid: 32768 blocks, 256 thr; each thread: 4 consecutive t.
// ---------------------------------------------------------------------------
__global__ __launch_bounds__(256) void cb_dw1x3(const float* __restrict__ b1,
                                                const float* __restrict__ ach,
                                                const float* __restrict__ w,
                                                float* __restrict__ out)
{
    const int gid = blockIdx.x * 256 + threadIdx.x;
    const int t0 = (gid & 127) << 2;
    const int r = gid >> 7;
    const int h = r & 63;
    const int bc = r >> 6;
    const int c = bc & 127;
    const float* p = b1 + ((size_t)bc * HH + h) * TT;
    const float av = ach[bc];
    const float w0 = w[c * 3 + 0], w1v = w[c * 3 + 1], w2v = w[c * 3 + 2];
    float4 mid = *(const float4*)&p[t0];
    float cbm1 = 0.f, cb4 = 0.f;
    if (t0 > 0) { float l = p[t0 - 1]; cbm1 = l * l * av; }
    if (t0 + 4 < TT) { float rr = p[t0 + 4]; cb4 = rr * rr * av; }
    float c0 = mid.x * mid.x * av, c1 = mid.y * mid.y * av;
    float c2 = mid.z * mid.z * av, c3 = mid.w * mid.w * av;
    float4 o;
    o.x = cbm1 * w0 + c0 * w1v + c1 * w2v;
    o.y = c0 * w0 + c1 * w1v + c2 * w2v;
    o.z = c1 * w0 + c2 * w1v + c3 * w2v;
    o.w = c2 * w0 + c3 * w1v + cb4 * w2v;
    *(float4*)&out[((size_t)bc * HH + h) * TT + t0] = o;
}

// ---------------------------------------------------------------------------
// Spatial pooling: per-pixel mean & max over channels. Grid 1024x256.
// s layout: [b][2][h][t]
// ---------------------------------------------------------------------------
__global__ __launch_bounds__(256) void spat_pool(const float* __restrict__ in,
                                                 float* __restrict__ s)
{
    const int pix = blockIdx.x * 256 + threadIdx.x;
    const int t = pix & 511, h = (pix >> 9) & 63, b = pix >> 15;
    const float* p = in + ((size_t)b * CC * HH + h) * TT + t;
    float sum = 0.f, mx = -3.4e38f;
#pragma unroll 8
    for (int c = 0; c < CC; ++c) {
        float v = p[(size_t)c * HW];
        sum += v; mx = fmaxf(mx, v);
    }
    const int sp = h * TT + t;
    s[((size_t)b * 2) * HW + sp] = sum * (1.f / (float)CC);
    s[((size_t)b * 2 + 1) * HW + sp] = mx;
}

// ---------------------------------------------------------------------------
// 7x7 conv on the 2-channel pooled map + sigmoid. Grid 1024x256.
// ---------------------------------------------------------------------------
__global__ __launch_bounds__(256) void spat_conv(const float* __restrict__ s,
                                                 const float* __restrict__ w,
                                                 float* __restrict__ a)
{
    __shared__ float wl[98];
    const int tid = threadIdx.x;
    if (tid < 98) wl[tid] = w[tid];
    __syncthreads();
    const int pix = blockIdx.x * 256 + tid;
    const int t = pix & 511, h = (pix >> 9) & 63, b = pix >> 15;
    float acc = 0.f;
#pragma unroll
    for (int ch = 0; ch < 2; ++ch) {
        const float* sp = s + ((size_t)b * 2 + ch) * HW;
#pragma unroll
        for (int di = 0; di < 7; ++di) {
            int hh = h + di - 3;
            if (hh < 0 || hh >= HH) continue;
#pragma unroll
            for (int dj = 0; dj < 7; ++dj) {
                int t2 = t + dj - 3;
                if (t2 < 0 || t2 >= TT) continue;
                acc += sp[hh * TT + t2] * wl[ch * 49 + di * 7 + dj];
            }
        }
    }
    a[pix] = sigf(acc);
}

// ---------------------------------------------------------------------------
// SSM scan (input-independent): computes sc[c][t] for both blocks.
// Grid: 2 blocks x 512 threads. Chunked affine scan: M^64 by squaring,
// entry states stitched serially (8 steps), 8 waves re-scan chunks.
// ---------------------------------------------------------------------------
__global__ __launch_bounds__(512) void scan_kernel(const float* __restrict__ A1,
                                                   const float* __restrict__ B1,
                                                   const float* __restrict__ C1,
                                                   const float* __restrict__ A2,
                                                   const float* __restrict__ B2,
                                                   const float* __restrict__ C2,
                                                   float* __restrict__ sc1,
                                                   float* __restrict__ sc2,
                                                   float* __restrict__ Sws)
{
    const float* A = blockIdx.x ? A2 : A1;
    const float* Bv = blockIdx.x ? B2 : B1;
    const float* Cm = blockIdx.x ? C2 : C1;
    float* sc = blockIdx.x ? sc2 : sc1;
    float* Sg = Sws + (size_t)blockIdx.x * (TT * 32);

    __shared__ float M[32][33];   // M[j][i] = A[i][j]  (z_new = z@M)
    __shared__ float P[32][33];   // becomes M^64
    __shared__ float Q[32][33];
    __shared__ float L64[32];
    __shared__ float Eq[8][32];
    __shared__ float Cs[32][128];

    const int tid = threadIdx.x;
    const int wave = tid >> 6, lane = tid & 63;

    for (int idx = tid; idx < 1024; idx += 512) {
        int j = idx >> 5, i = idx & 31;
        float v = A[i * 32 + j];
        M[j][i] = v; P[j][i] = v;
    }
    for (int idx = tid; idx < 4096; idx += 512) Cs[idx >> 7][idx & 127] = Cm[idx];
    __syncthreads();

    // P = M^64 via 6 squarings
    for (int sq = 0; sq < 6; ++sq) {
        for (int idx = tid; idx < 1024; idx += 512) {
            int r = idx >> 5, c2 = idx & 31;
            float acc = 0.f;
#pragma unroll
            for (int k = 0; k < 32; ++k) acc += P[r][k] * P[k][c2];
            Q[r][c2] = acc;
        }
        __syncthreads();
        for (int idx = tid; idx < 1024; idx += 512) {
            int r = idx >> 5, c2 = idx & 31;
            P[r][c2] = Q[r][c2];
        }
        __syncthreads();
    }

    // wave 0: L64 (64 steps from zero state)
    if (wave == 0) {
        float bval = (lane < 32) ? Bv[lane] : 0.f;
        float z = 0.f;
        for (int r = 0; r < 64; ++r) {
            float zn = bval;
#pragma unroll
            for (int j = 0; j < 32; ++j) zn += __shfl(z, j, 64) * M[j][lane & 31];
            z = zn;
        }
        if (lane < 32) L64[lane] = z;
    }
    __syncthreads();

    // wave 0: entry states E_q
    if (wave == 0) {
        float e = 0.f;
        if (lane < 32) Eq[0][lane] = 0.f;
        for (int q = 1; q < 8; ++q) {
            float en = (lane < 32) ? L64[lane] : 0.f;
#pragma unroll
            for (int j = 0; j < 32; ++j) en += __shfl(e, j, 64) * P[j][lane & 31];
            e = en;
            if (lane < 32) Eq[q][lane] = e;
        }
    }
    __syncthreads();

    // all 8 waves: re-scan chunks, write S to global scratch
    {
        float bval = (lane < 32) ? Bv[lane] : 0.f;
        float z = (lane < 32) ? Eq[wave][lane] : 0.f;
        for (int r = 0; r < 64; ++r) {
            float zn = bval;
#pragma unroll
            for (int j = 0; j < 32; ++j) zn += __shfl(z, j, 64) * M[j][lane & 31];
            z = zn;
            if (lane < 32) Sg[(wave * 64 + r) * 32 + lane] = z;
        }
    }
    __syncthreads();

    // sc[c][t] = S[t] . Cm[:,c]
    {
        float sreg[32];
#pragma unroll
        for (int j = 0; j < 32; ++j) sreg[j] = Sg[tid * 32 + j];
        for (int c = 0; c < 128; ++c) {
            float acc = 0.f;
#pragma unroll
            for (int j = 0; j < 32; ++j) acc += sreg[j] * Cs[j][c];
            sc[c * TT + tid] = acc;
        }
    }
}

// ---------------------------------------------------------------------------
// SSM apply + LayerNorm + multiply by spatial branch (LDS-tiled, low-VGPR).
// out[b,c,h,t] = LN_c(cb2 + gelu(sc[c,t] + cb2*D[c])) * sigmoid(b2^2 * aspat)
// Grid: 4096 blocks (b*h*ttile), 256 threads. Block owns [128 c][64 t] tile.
// Thread (g=tid>>6, tl=tid&63): channels c=4i+g (wave-uniform c), t=tl.
// tile writes/reads: 2-way bank alias only (free). VGPR ~48 -> high occupancy.
// ---------------------------------------------------------------------------
__global__ __launch_bounds__(256) void ssm_apply(const float* __restrict__ cb2,
                                                 const float* __restrict__ b2,
                                                 const float* __restrict__ aspat,
                                                 const float* __restrict__ sc,
                                                 const float* __restrict__ Dv,
                                                 const float* __restrict__ ln,
                                                 float* __restrict__ out)
{
    __shared__ float tile[128][64];
    __shared__ float psum[4][64], psq[4][64];
    __shared__ float smu[64], srstd[64];
    __shared__ float sas[64];
    const int tid = threadIdx.x;
    const int bid = blockIdx.x;                 // = ((b*64)+h)*8 + ttile
    const int ttile = bid & 7, h = (bid >> 3) & 63, b = bid >> 9;
    const int t0 = ttile << 6;
    const int tl = tid & 63, g = tid >> 6;
    const size_t base = (size_t)b * CC * HW + (size_t)h * TT + t0;

    if (tid < 64) sas[tid] = aspat[((size_t)b * HH + h) * TT + t0 + tid];

    float s = 0.f, sq = 0.f;
#pragma unroll
    for (int i = 0; i < 32; ++i) {
        int c = 4 * i + g;                      // wave-uniform c
        float x = cb2[base + (size_t)c * HW + tl];
        float z = sc[c * TT + t0 + tl] + x * Dv[c];
        float o = x + geluf(z);
        tile[c][tl] = o;
        s += o; sq += o * o;
    }
    psum[g][tl] = s; psq[g][tl] = sq;
    __syncthreads();
    if (tid < 64) {
        float su = psum[0][tid] + psum[1][tid] + psum[2][tid] + psum[3][tid];
        float qu = psq[0][tid] + psq[1][tid] + psq[2][tid] + psq[3][tid];
        float mu = su * (1.f / 128.f);
        float var = qu * (1.f / 128.f) - mu * mu;
        smu[tid] = mu;
        srstd[tid] = rsqrtf(var + EPSF);
    }
    __syncthreads();

    const float mu = smu[tl], rstd = srstd[tl], asv = sas[tl];
#pragma unroll
    for (int i = 0; i < 32; ++i) {
        int c = 4 * i + g;
        float lnw = ln[c], lnb = ln[CC + c];
        float val = (tile[c][tl] - mu) * rstd * lnw + lnb;
        float bv = b2[base + (size_t)c * HW + tl];
        float sb = sigf(bv * bv * asv);
        out[base + (size_t)c * HW + tl] = val * sb;
    }
}

// ---------------------------------------------------------------------------
// Host-side launch
// ---------------------------------------------------------------------------
extern "C" void kernel_launch(void* const* d_in, const int* in_sizes, int n_in,
                              void* d_out, int out_size, void* d_ws, size_t ws_size,
                              hipStream_t stream)
{
    (void)in_sizes; (void)n_in; (void)out_size; (void)ws_size;

    auto pf = [&](int i) { return (const float*)d_in[i]; };

    const float* x = pf(0);
    const float* w_in = pf(1);
    const float* w_out = pf(2);
    const float* bn_out = pf(3);

    float* W = (float*)d_ws;
    const size_t NT = (size_t)BB * CC * HH * TT;      // 33554432
    float* S0 = W;
    float* S1 = W + NT;
    float* sc1 = W + 2 * NT;
    float* sc2 = sc1 + CC * TT;
    float* Sws = sc2 + CC * TT;                       // 2*512*32
    float* pavg = Sws + 2 * TT * 32;
    float* pmax = pavg + BB * CC;
    float* achan = pmax + BB * CC;
    float* sspat = achan + BB * CC;                   // 8*2*32768
    float* aspat = sspat + (size_t)BB * 2 * HW;       // 262144
    float* OUT = (float*)d_out;

    const dim3 blk(256);
    const int PW_GRID = (BB * HH) * (TT / 64);        // 4096
    const int DW_GRID = BB * CC * (HH / 16) * (TT / 64); // 32768
    const int PIX_GRID = NPIX / 256;                  // 1024
    const int D1_GRID = (BB * CC * HH * (TT / 4)) / 256; // 32768
    const int SA_GRID = 4096;                         // ssm_apply tiles

    // SSM tables for both blocks (input independent)
    scan_kernel<<<2, 512, 0, stream>>>(pf(16), pf(17), pf(18), pf(33), pf(34), pf(35), sc1, sc2, Sws);

    // stem: x = pw(x, w_in)
    pw_kernel<64, 0, false, false><<<PW_GRID, blk, 0, stream>>>(x, w_in, nullptr, S0);

    auto run_block = [&](int pb, const float* I, float* Iw, float* U, float* V,
                         bool flip, const float* scp) {
        // I==Iw (const alias). dw5x5 both branches: I -> U (Da), V (Db)
        if (flip)
            dw5x5_dual<true><<<DW_GRID, blk, 0, stream>>>(I, pf(pb + 0), pf(pb + 3), U, V);
        else
            dw5x5_dual<false><<<DW_GRID, blk, 0, stream>>>(I, pf(pb + 0), pf(pb + 3), U, V);
        // b1 = relu(bn(pw(Da))) -> Iw ; b2 = relu(bn(pw(Db))) -> U
        pw_kernel<128, 1, false, true><<<PW_GRID, blk, 0, stream>>>(U, pf(pb + 1), pf(pb + 2), Iw);
        pw_kernel<128, 1, false, true><<<PW_GRID, blk, 0, stream>>>(V, pf(pb + 4), pf(pb + 5), U);
        // channel attention on b1
        chan_pool<<<BB * CC, blk, 0, stream>>>(Iw, pavg, pmax);
        chan_mlp<<<1, blk, 0, stream>>>(pavg, pmax, pf(pb + 6), pf(pb + 7), achan);
        // cb chain: (b1^2*a) -> dw1x3 -> V ; pw+bn+sigmoid -> Iw (cb2)
        cb_dw1x3<<<D1_GRID, blk, 0, stream>>>(Iw, achan, pf(pb + 9), V);
        pw_kernel<128, 2, false, true><<<PW_GRID, blk, 0, stream>>>(V, pf(pb + 10), pf(pb + 11), Iw);
        // spatial attention on b2 (U)
        spat_pool<<<PIX_GRID, blk, 0, stream>>>(U, sspat);
        spat_conv<<<PIX_GRID, blk, 0, stream>>>(sspat, pf(pb + 8), aspat);
        // ssm apply + LN + * sb  -> V
        ssm_apply<<<SA_GRID, blk, 0, stream>>>(Iw, U, aspat, scp, pf(pb + 15), pf(pb + 16), V);
        // block output now in V
    };

    // block 1: I=S0, U=S1, V=OUT -> out in OUT
    run_block(4, S0, S0, S1, OUT, false, sc1);
    // block 2 (reads flipped): I=OUT, U=S0, V=S1 -> out in S1 (flipped space)
    run_block(21, OUT, OUT, S0, S1, true, sc2);
    // final: relu(bn(pw(flip(S1), w_out))) -> d_out
    pw_kernel<128, 1, true, true><<<PW_GRID, blk, 0, stream>>>(S1, w_out, bn_out, OUT);
}

// Round 3
// 1031.116 us; speedup vs baseline: 3.6726x; 2.8382x over previous
//
#include <hip/hip_runtime.h>
#include <cstdint>
#include <cstddef>

#define EPSF 1e-5f

// Dims (fixed by the problem)
#define BB 8
#define CC 128
#define HH 64
#define TT 512
#define HW (HH*TT)          // 32768
#define NPIX (BB*HH*TT)     // 262144

__device__ __forceinline__ float sigf(float x) { return 1.f / (1.f + expf(-x)); }
__device__ __forceinline__ float geluf(float z) { return 0.5f * z * (1.f + erff(z * 0.70710678118654752f)); }

// bf16 <-> f32 (RNE)
__device__ __forceinline__ unsigned short f2u(float f) {
    unsigned int u = __builtin_bit_cast(unsigned int, f);
    u += 0x7fffu + ((u >> 16) & 1u);
    return (unsigned short)(u >> 16);
}
__device__ __forceinline__ float u2f(unsigned short s) {
    return __builtin_bit_cast(float, (unsigned int)s << 16);
}

typedef __attribute__((ext_vector_type(8))) short bf16x8;
typedef __attribute__((ext_vector_type(4))) float f32x4;

// ---------------------------------------------------------------------------
// Weight prep: convert 8 pw weight matrices f32 -> bf16 into slots of 16384.
// slot0: w_in (8192 used), 1:b1_pwa 2:b1_pwb 3:b1_d1p 4:b2_pwa 5:b2_pwb
// 6:b2_d1p 7:w_out
// ---------------------------------------------------------------------------
__global__ __launch_bounds__(256) void prep_weights(const float* __restrict__ s0,
                                                    const float* __restrict__ s1,
                                                    const float* __restrict__ s2,
                                                    const float* __restrict__ s3,
                                                    const float* __restrict__ s4,
                                                    const float* __restrict__ s5,
                                                    const float* __restrict__ s6,
                                                    const float* __restrict__ s7,
                                                    unsigned short* __restrict__ wbf)
{
    int gid = blockIdx.x * 256 + threadIdx.x;     // 0..131071
    int slot = gid >> 14, off = gid & 16383;
    const float* srcs[8] = {s0, s1, s2, s3, s4, s5, s6, s7};
    float v = 0.f;
    if (slot != 0 || off < 8192) v = srcs[slot][off];
    wbf[gid] = f2u(v);
}

// ---------------------------------------------------------------------------
// Pointwise conv via bf16 MFMA.  out[b,o,h,t] = act(bn(sum_c in[b,c,h,t]*W[o,c]))
// Grid 4096 blocks (b,h,ttile), 256 threads (4 waves). Block: 128 o x 64 t.
// Wave w: o in [32w,32w+32). LDS: W[128][CIN+8] bf16, X[t=64][CIN+8] bf16
// (transposed during staging; +8 pad -> 4-bank row stride, 2-way max = free).
// ---------------------------------------------------------------------------
template<int CIN, int ACT, bool FLIP, bool BN, bool INF32, bool OUTF32>
__global__ __launch_bounds__(256) void pw_mfma(const void* __restrict__ inv,
                                               const unsigned short* __restrict__ Wb,
                                               const float* __restrict__ bnp,
                                               void* __restrict__ outv)
{
    constexpr int CSTR = CIN + 8;
    constexpr int CP = CIN / 32;          // c-rows per staging thread
    __shared__ unsigned short Wl[128 * CSTR];
    __shared__ unsigned short Xl[64 * CSTR];
    __shared__ float bns[128], bnh[128];

    const int tid = threadIdx.x;
    const int bh = blockIdx.x >> 3, tt = blockIdx.x & 7;
    const int b = bh >> 6, h = bh & 63;
    const int t0 = tt << 6;

    if (BN && tid < 128) {
        float g = bnp[tid], be = bnp[CC + tid], m = bnp[2 * CC + tid], v = bnp[3 * CC + tid];
        float s = g * rsqrtf(v + EPSF);
        bns[tid] = s; bnh[tid] = be - m * s;
    }

    // ---- stage W (bf16, row-major o x c, padded rows) ----
    {
        constexpr int L = (128 * CIN) / (256 * 8);
#pragma unroll
        for (int i = 0; i < L; ++i) {
            int idx = (i * 256 + tid) * 8;
            int o = idx / CIN, c = idx % CIN;
            *(uint4*)&Wl[o * CSTR + c] = *(const uint4*)&Wb[o * CIN + c];
        }
    }
    // ---- stage X transposed: Xl[t][c] ----
    {
        const int s = tid & 7, g = tid >> 3;
        const int tl0 = s * 8;
        const int c0 = g * CP;
        unsigned short vals[CP][8];
#pragma unroll
        for (int i = 0; i < CP; ++i) {
            const size_t rowbase = ((size_t)(b * CIN + c0 + i) * HH + h) * TT;
            const int tb = FLIP ? (504 - t0 - tl0) : (t0 + tl0);
            if (INF32) {
                const float* pf32 = (const float*)inv;
                float4 u0 = *(const float4*)&pf32[rowbase + tb];
                float4 u1 = *(const float4*)&pf32[rowbase + tb + 4];
                float tmp[8] = {u0.x, u0.y, u0.z, u0.w, u1.x, u1.y, u1.z, u1.w};
#pragma unroll
                for (int j = 0; j < 8; ++j) vals[i][j] = f2u(tmp[FLIP ? 7 - j : j]);
            } else {
                const unsigned short* pb = (const unsigned short*)inv;
                unsigned short tmp[8];
                *(uint4*)tmp = *(const uint4*)&pb[rowbase + tb];
#pragma unroll
                for (int j = 0; j < 8; ++j) vals[i][j] = tmp[FLIP ? 7 - j : j];
            }
        }
#pragma unroll
        for (int j = 0; j < 8; ++j) {
            unsigned short* dst = &Xl[(tl0 + j) * CSTR + c0];
            if (CP == 4) {
                uint2 pk;
                pk.x = (unsigned)vals[0][j] | ((unsigned)vals[1][j] << 16);
                pk.y = (unsigned)vals[2][j] | ((unsigned)vals[3][j] << 16);
                *(uint2*)dst = pk;
            } else {
                *(unsigned int*)dst = (unsigned)vals[0][j] | ((unsigned)vals[1][j] << 16);
            }
        }
    }
    __syncthreads();

    // ---- MFMA compute: wave tile 32 o x 64 t ----
    const int lane = tid & 63, wv = tid >> 6;
    const int lanel = lane & 15, laneh = lane >> 4;
    const int ob = wv * 32;

    f32x4 acc[2][4];
#pragma unroll
    for (int f = 0; f < 2; ++f)
#pragma unroll
        for (int tf = 0; tf < 4; ++tf) acc[f][tf] = (f32x4){0.f, 0.f, 0.f, 0.f};

#pragma unroll
    for (int ks = 0; ks < CIN / 32; ++ks) {
        const int kb = ks * 32 + laneh * 8;
        bf16x8 a0 = *(const bf16x8*)&Wl[(ob + lanel) * CSTR + kb];
        bf16x8 a1 = *(const bf16x8*)&Wl[(ob + 16 + lanel) * CSTR + kb];
#pragma unroll
        for (int tf = 0; tf < 4; ++tf) {
            bf16x8 bb = *(const bf16x8*)&Xl[(tf * 16 + lanel) * CSTR + kb];
            acc[0][tf] = __builtin_amdgcn_mfma_f32_16x16x32_bf16(a0, bb, acc[0][tf], 0, 0, 0);
            acc[1][tf] = __builtin_amdgcn_mfma_f32_16x16x32_bf16(a1, bb, acc[1][tf], 0, 0, 0);
        }
    }

    // ---- epilogue: BN + act + store (D: row=(lane>>4)*4+r, col=lane&15) ----
    const size_t obase = ((size_t)(b * CC) * HH + h) * TT;
#pragma unroll
    for (int f = 0; f < 2; ++f) {
#pragma unroll
        for (int r = 0; r < 4; ++r) {
            const int row = ob + f * 16 + laneh * 4 + r;
            const float s = BN ? bns[row] : 1.f;
            const float sh = BN ? bnh[row] : 0.f;
#pragma unroll
            for (int tf = 0; tf < 4; ++tf) {
                float v = acc[f][tf][r] * s + sh;
                if (ACT == 1) v = fmaxf(v, 0.f);
                if (ACT == 2) v = sigf(v);
                size_t oidx = obase + (size_t)row * HW + t0 + tf * 16 + lanel;
                if (OUTF32) ((float*)outv)[oidx] = v;
                else ((unsigned short*)outv)[oidx] = f2u(v);
            }
        }
    }
}

// ---------------------------------------------------------------------------
// Depthwise 5x5 'same' conv (bf16 in/out, f32 compute), dual weight sets.
// Grid 32768 blocks, 256 threads; 16x64 tile.
// ---------------------------------------------------------------------------
template<bool FLIP>
__global__ __launch_bounds__(256) void dw5x5_dual(const unsigned short* __restrict__ in,
                                                  const float* __restrict__ wa,
                                                  const float* __restrict__ wb,
                                                  unsigned short* __restrict__ oa,
                                                  unsigned short* __restrict__ ob)
{
    __shared__ float tile[20][68];
    __shared__ float wla[25], wlb[25];
    const int tid = threadIdx.x;
    const int bc = blockIdx.x >> 5;
    const int tl5 = blockIdx.x & 31;
    const int ht = tl5 >> 3, ttile = tl5 & 7;
    const int h0 = ht << 4, t0 = ttile << 6;
    const int c = bc & (CC - 1);
    const unsigned short* base = in + (size_t)bc * HW;

    if (tid < 25) { wla[tid] = wa[c * 25 + tid]; wlb[tid] = wb[c * 25 + tid]; }
    for (int idx = tid; idx < 20 * 68; idx += 256) {
        int hl = idx / 68, tl = idx % 68;
        int hh = h0 + hl - 2, t2 = t0 + tl - 2;
        float v = 0.f;
        if (hh >= 0 && hh < HH && t2 >= 0 && t2 < TT)
            v = u2f(base[hh * TT + (FLIP ? (TT - 1) - t2 : t2)]);
        tile[hl][tl] = v;
    }
    __syncthreads();
#pragma unroll
    for (int rep = 0; rep < 4; ++rep) {
        int oi = rep * 256 + tid;
        int hl = oi >> 6, tl = oi & 63;
        float sa = 0.f, sb = 0.f;
#pragma unroll
        for (int di = 0; di < 5; ++di)
#pragma unroll
            for (int dj = 0; dj < 5; ++dj) {
                float x = tile[hl + di][tl + dj];
                sa += x * wla[di * 5 + dj];
                sb += x * wlb[di * 5 + dj];
            }
        size_t off = (size_t)bc * HW + (h0 + hl) * TT + t0 + tl;
        oa[off] = f2u(sa); ob[off] = f2u(sb);
    }
}

// ---------------------------------------------------------------------------
// Channel pooling (bf16 in): per (b,c) mean & max. Grid 1024 x 256.
// ---------------------------------------------------------------------------
__global__ __launch_bounds__(256) void chan_pool(const unsigned short* __restrict__ in,
                                                 float* __restrict__ pavg,
                                                 float* __restrict__ pmax)
{
    __shared__ float ssum[256], smax[256];
    const int bc = blockIdx.x, tid = threadIdx.x;
    const uint4* p4 = (const uint4*)(in + (size_t)bc * HW);
    float s = 0.f, m = -3.4e38f;
    for (int i = tid; i < HW / 8; i += 256) {
        uint4 u = p4[i];
        unsigned w[4] = {u.x, u.y, u.z, u.w};
#pragma unroll
        for (int k = 0; k < 4; ++k) {
            float f0 = __builtin_bit_cast(float, w[k] << 16);
            float f1 = __builtin_bit_cast(float, w[k] & 0xffff0000u);
            s += f0 + f1; m = fmaxf(m, fmaxf(f0, f1));
        }
    }
    ssum[tid] = s; smax[tid] = m;
    __syncthreads();
    for (int w2 = 128; w2 > 0; w2 >>= 1) {
        if (tid < w2) { ssum[tid] += ssum[tid + w2]; smax[tid] = fmaxf(smax[tid], smax[tid + w2]); }
        __syncthreads();
    }
    if (tid == 0) { pavg[bc] = ssum[0] * (1.f / (float)HW); pmax[bc] = smax[0]; }
}

// ---------------------------------------------------------------------------
// Channel-attention MLP (f32 small). One block, 256 threads.
// ---------------------------------------------------------------------------
__global__ __launch_bounds__(256) void chan_mlp(const float* __restrict__ pavg,
                                                const float* __restrict__ pmax,
                                                const float* __restrict__ w1,
                                                const float* __restrict__ w2,
                                                float* __restrict__ a)
{
    __shared__ float ua[8][128], um[8][128], hida[8][8], hidm[8][8];
    const int tid = threadIdx.x;
    for (int idx = tid; idx < 1024; idx += 256) {
        ua[idx >> 7][idx & 127] = pavg[idx];
        um[idx >> 7][idx & 127] = pmax[idx];
    }
    __syncthreads();
    if (tid < 128) {
        int b = tid >> 4, m = (tid >> 1) & 7, path = tid & 1;
        const float* u = path ? um[b] : ua[b];
        float acc = 0.f;
#pragma unroll
        for (int cc2 = 0; cc2 < 128; ++cc2) acc += u[cc2] * w1[m * 128 + cc2];
        acc = fmaxf(acc, 0.f);
        if (path) hidm[b][m] = acc; else hida[b][m] = acc;
    }
    __syncthreads();
    for (int idx = tid; idx < 1024; idx += 256) {
        int b = idx >> 7, cc2 = idx & 127;
        float acc = 0.f;
#pragma unroll
        for (int m = 0; m < 8; ++m) acc += (hida[b][m] + hidm[b][m]) * w2[cc2 * 8 + m];
        a[idx] = sigf(acc);
    }
}

// ---------------------------------------------------------------------------
// cb = b1^2 * a[b,c] then depthwise 1x3 conv along t (bf16 in/out).
// Grid 16384 x 256; thread: 8 consecutive t.
// ---------------------------------------------------------------------------
__global__ __launch_bounds__(256) void cb_dw1x3(const unsigned short* __restrict__ b1,
                                                const float* __restrict__ ach,
                                                const float* __restrict__ w,
                                                unsigned short* __restrict__ out)
{
    const int gid = blockIdx.x * 256 + threadIdx.x;
    const int t0 = (gid & 63) << 3;
    const int r = gid >> 6;
    const int h = r & 63;
    const int bc = r >> 6;
    const int c = bc & 127;
    const unsigned short* p = b1 + ((size_t)bc * HH + h) * TT;
    const float av = ach[bc];
    const float w0 = w[c * 3 + 0], w1v = w[c * 3 + 1], w2v = w[c * 3 + 2];
    unsigned short raw[8];
    *(uint4*)raw = *(const uint4*)&p[t0];
    float cb[10];
    { float l = (t0 > 0) ? u2f(p[t0 - 1]) : 0.f; cb[0] = (t0 > 0) ? l * l * av : 0.f; }
    { float rr = (t0 + 8 < TT) ? u2f(p[t0 + 8]) : 0.f; cb[9] = (t0 + 8 < TT) ? rr * rr * av : 0.f; }
#pragma unroll
    for (int j = 0; j < 8; ++j) { float x = u2f(raw[j]); cb[j + 1] = x * x * av; }
    unsigned short o8[8];
#pragma unroll
    for (int j = 0; j < 8; ++j) o8[j] = f2u(cb[j] * w0 + cb[j + 1] * w1v + cb[j + 2] * w2v);
    *(uint4*)&out[((size_t)bc * HH + h) * TT + t0] = *(uint4*)o8;
}

// ---------------------------------------------------------------------------
// Spatial pooling (bf16 in): per-pixel mean & max over channels. Grid 1024x256.
// ---------------------------------------------------------------------------
__global__ __launch_bounds__(256) void spat_pool(const unsigned short* __restrict__ in,
                                                 float* __restrict__ s)
{
    const int pix = blockIdx.x * 256 + threadIdx.x;
    const int t = pix & 511, h = (pix >> 9) & 63, b = pix >> 15;
    const unsigned short* p = in + ((size_t)b * CC * HH + h) * TT + t;
    float sum = 0.f, mx = -3.4e38f;
#pragma unroll 8
    for (int c = 0; c < CC; ++c) {
        float v = u2f(p[(size_t)c * HW]);
        sum += v; mx = fmaxf(mx, v);
    }
    const int sp = h * TT + t;
    s[((size_t)b * 2) * HW + sp] = sum * (1.f / (float)CC);
    s[((size_t)b * 2 + 1) * HW + sp] = mx;
}

// ---------------------------------------------------------------------------
// 7x7 conv on 2-ch pooled map + sigmoid (f32). Grid 1024x256.
// ---------------------------------------------------------------------------
__global__ __launch_bounds__(256) void spat_conv(const float* __restrict__ s,
                                                 const float* __restrict__ w,
                                                 float* __restrict__ a)
{
    __shared__ float wl[98];
    const int tid = threadIdx.x;
    if (tid < 98) wl[tid] = w[tid];
    __syncthreads();
    const int pix = blockIdx.x * 256 + tid;
    const int t = pix & 511, h = (pix >> 9) & 63, b = pix >> 15;
    float acc = 0.f;
#pragma unroll
    for (int ch = 0; ch < 2; ++ch) {
        const float* sp = s + ((size_t)b * 2 + ch) * HW;
#pragma unroll
        for (int di = 0; di < 7; ++di) {
            int hh = h + di - 3;
            if (hh < 0 || hh >= HH) continue;
#pragma unroll
            for (int dj = 0; dj < 7; ++dj) {
                int t2 = t + dj - 3;
                if (t2 < 0 || t2 >= TT) continue;
                acc += sp[hh * TT + t2] * wl[ch * 49 + di * 7 + dj];
            }
        }
    }
    a[pix] = sigf(acc);
}

// ---------------------------------------------------------------------------
// SSM scan (input-independent): sc[c][t] for both blocks. f32.
// ---------------------------------------------------------------------------
__global__ __launch_bounds__(512) void scan_kernel(const float* __restrict__ A1,
                                                   const float* __restrict__ B1,
                                                   const float* __restrict__ C1,
                                                   const float* __restrict__ A2,
                                                   const float* __restrict__ B2,
                                                   const float* __restrict__ C2,
                                                   float* __restrict__ sc1,
                                                   float* __restrict__ sc2,
                                                   float* __restrict__ Sws)
{
    const float* A = blockIdx.x ? A2 : A1;
    const float* Bv = blockIdx.x ? B2 : B1;
    const float* Cm = blockIdx.x ? C2 : C1;
    float* sc = blockIdx.x ? sc2 : sc1;
    float* Sg = Sws + (size_t)blockIdx.x * (TT * 32);

    __shared__ float M[32][33];
    __shared__ float P[32][33];
    __shared__ float Q[32][33];
    __shared__ float L64[32];
    __shared__ float Eq[8][32];
    __shared__ float Cs[32][128];

    const int tid = threadIdx.x;
    const int wave = tid >> 6, lane = tid & 63;

    for (int idx = tid; idx < 1024; idx += 512) {
        int j = idx >> 5, i = idx & 31;
        float v = A[i * 32 + j];
        M[j][i] = v; P[j][i] = v;
    }
    for (int idx = tid; idx < 4096; idx += 512) Cs[idx >> 7][idx & 127] = Cm[idx];
    __syncthreads();

    for (int sq = 0; sq < 6; ++sq) {
        for (int idx = tid; idx < 1024; idx += 512) {
            int r = idx >> 5, c2 = idx & 31;
            float acc = 0.f;
#pragma unroll
            for (int k = 0; k < 32; ++k) acc += P[r][k] * P[k][c2];
            Q[r][c2] = acc;
        }
        __syncthreads();
        for (int idx = tid; idx < 1024; idx += 512) {
            int r = idx >> 5, c2 = idx & 31;
            P[r][c2] = Q[r][c2];
        }
        __syncthreads();
    }

    if (wave == 0) {
        float bval = (lane < 32) ? Bv[lane] : 0.f;
        float z = 0.f;
        for (int r = 0; r < 64; ++r) {
            float zn = bval;
#pragma unroll
            for (int j = 0; j < 32; ++j) zn += __shfl(z, j, 64) * M[j][lane & 31];
            z = zn;
        }
        if (lane < 32) L64[lane] = z;
    }
    __syncthreads();

    if (wave == 0) {
        float e = 0.f;
        if (lane < 32) Eq[0][lane] = 0.f;
        for (int q = 1; q < 8; ++q) {
            float en = (lane < 32) ? L64[lane] : 0.f;
#pragma unroll
            for (int j = 0; j < 32; ++j) en += __shfl(e, j, 64) * P[j][lane & 31];
            e = en;
            if (lane < 32) Eq[q][lane] = e;
        }
    }
    __syncthreads();

    {
        float bval = (lane < 32) ? Bv[lane] : 0.f;
        float z = (lane < 32) ? Eq[wave][lane] : 0.f;
        for (int r = 0; r < 64; ++r) {
            float zn = bval;
#pragma unroll
            for (int j = 0; j < 32; ++j) zn += __shfl(z, j, 64) * M[j][lane & 31];
            z = zn;
            if (lane < 32) Sg[(wave * 64 + r) * 32 + lane] = z;
        }
    }
    __syncthreads();

    {
        float sreg[32];
#pragma unroll
        for (int j = 0; j < 32; ++j) sreg[j] = Sg[tid * 32 + j];
        for (int c = 0; c < 128; ++c) {
            float acc = 0.f;
#pragma unroll
            for (int j = 0; j < 32; ++j) acc += sreg[j] * Cs[j][c];
            sc[c * TT + tid] = acc;
        }
    }
}

// ---------------------------------------------------------------------------
// SSM apply + LayerNorm + spatial-branch multiply (LDS-tiled).
// cb2 f32, b2 bf16, out bf16. Grid 4096 x 256.
// ---------------------------------------------------------------------------
__global__ __launch_bounds__(256) void ssm_apply(const float* __restrict__ cb2,
                                                 const unsigned short* __restrict__ b2,
                                                 const float* __restrict__ aspat,
                                                 const float* __restrict__ sc,
                                                 const float* __restrict__ Dv,
                                                 const float* __restrict__ ln,
                                                 unsigned short* __restrict__ out)
{
    __shared__ float tile[128][64];
    __shared__ float psum[4][64], psq[4][64];
    __shared__ float smu[64], srstd[64];
    __shared__ float sas[64];
    const int tid = threadIdx.x;
    const int bid = blockIdx.x;
    const int ttile = bid & 7, h = (bid >> 3) & 63, b = bid >> 9;
    const int t0 = ttile << 6;
    const int tl = tid & 63, g = tid >> 6;
    const size_t base = (size_t)b * CC * HW + (size_t)h * TT + t0;

    if (tid < 64) sas[tid] = aspat[((size_t)b * HH + h) * TT + t0 + tid];

    float s = 0.f, sq = 0.f;
#pragma unroll
    for (int i = 0; i < 32; ++i) {
        int c = 4 * i + g;
        float x = cb2[base + (size_t)c * HW + tl];
        float z = sc[c * TT + t0 + tl] + x * Dv[c];
        float o = x + geluf(z);
        tile[c][tl] = o;
        s += o; sq += o * o;
    }
    psum[g][tl] = s; psq[g][tl] = sq;
    __syncthreads();
    if (tid < 64) {
        float su = psum[0][tid] + psum[1][tid] + psum[2][tid] + psum[3][tid];
        float qu = psq[0][tid] + psq[1][tid] + psq[2][tid] + psq[3][tid];
        float mu = su * (1.f / 128.f);
        float var = qu * (1.f / 128.f) - mu * mu;
        smu[tid] = mu;
        srstd[tid] = rsqrtf(var + EPSF);
    }
    __syncthreads();

    const float mu = smu[tl], rstd = srstd[tl], asv = sas[tl];
#pragma unroll
    for (int i = 0; i < 32; ++i) {
        int c = 4 * i + g;
        float lnw = ln[c], lnb = ln[CC + c];
        float val = (tile[c][tl] - mu) * rstd * lnw + lnb;
        float bv = u2f(b2[base + (size_t)c * HW + tl]);
        float sb = sigf(bv * bv * asv);
        out[base + (size_t)c * HW + tl] = f2u(val * sb);
    }
}

// ---------------------------------------------------------------------------
// Host-side launch
// ---------------------------------------------------------------------------
extern "C" void kernel_launch(void* const* d_in, const int* in_sizes, int n_in,
                              void* d_out, int out_size, void* d_ws, size_t ws_size,
                              hipStream_t stream)
{
    (void)in_sizes; (void)n_in; (void)out_size; (void)ws_size;

    auto pf = [&](int i) { return (const float*)d_in[i]; };

    const float* x = pf(0);

    const size_t NT = (size_t)BB * CC * HH * TT;      // 33554432
    unsigned short* B0 = (unsigned short*)d_ws;
    unsigned short* B1 = B0 + NT;
    unsigned short* B2 = B1 + NT;
    unsigned short* wbf = B2 + NT;                    // 8 x 16384 bf16
    float* sc1 = (float*)(wbf + 8 * 16384);
    float* sc2 = sc1 + CC * TT;
    float* Sws = sc2 + CC * TT;                       // 2*512*32
    float* pavg = Sws + 2 * TT * 32;
    float* pmax = pavg + BB * CC;
    float* achan = pmax + BB * CC;
    float* sspat = achan + BB * CC;                   // 8*2*32768
    float* aspat = sspat + (size_t)BB * 2 * HW;       // 262144
    float* cb2 = (float*)d_out;                       // f32 scratch until final
    float* OUT = (float*)d_out;

    const dim3 blk(256);
    const int PW_GRID = 4096;
    const int DW_GRID = 32768;
    const int PIX_GRID = NPIX / 256;                  // 1024
    const int D1_GRID = 16384;

    prep_weights<<<512, blk, 0, stream>>>(pf(1), pf(5), pf(8), pf(14),
                                          pf(22), pf(25), pf(31), pf(2), wbf);
    scan_kernel<<<2, 512, 0, stream>>>(pf(16), pf(17), pf(18), pf(33), pf(34), pf(35),
                                       sc1, sc2, Sws);

    // stem: x(f32) -> B0 (bf16)
    pw_mfma<64, 0, false, false, true, false><<<PW_GRID, blk, 0, stream>>>(x, wbf + 0, nullptr, B0);

    auto run_block = [&](int pb, int wslot, const float* scp, bool flip) {
        // dw5x5 both branches: B0 -> B1(Da), B2(Db)
        if (flip)
            dw5x5_dual<true><<<DW_GRID, blk, 0, stream>>>(B0, pf(pb + 0), pf(pb + 3), B1, B2);
        else
            dw5x5_dual<false><<<DW_GRID, blk, 0, stream>>>(B0, pf(pb + 0), pf(pb + 3), B1, B2);
        // b1 = relu(bn(pw(Da))) -> B0 ; b2 = relu(bn(pw(Db))) -> B1
        pw_mfma<128, 1, false, true, false, false><<<PW_GRID, blk, 0, stream>>>(
            B1, wbf + (size_t)wslot * 16384, pf(pb + 2), B0);
        pw_mfma<128, 1, false, true, false, false><<<PW_GRID, blk, 0, stream>>>(
            B2, wbf + (size_t)(wslot + 1) * 16384, pf(pb + 5), B1);
        // channel attention on b1 (B0)
        chan_pool<<<BB * CC, blk, 0, stream>>>(B0, pavg, pmax);
        chan_mlp<<<1, blk, 0, stream>>>(pavg, pmax, pf(pb + 6), pf(pb + 7), achan);
        // cb chain: (b1^2*a) -> dw1x3 -> B2 ; pw+bn+sigmoid -> cb2 (f32, d_out)
        cb_dw1x3<<<D1_GRID, blk, 0, stream>>>(B0, achan, pf(pb + 9), B2);
        pw_mfma<128, 2, false, true, false, true><<<PW_GRID, blk, 0, stream>>>(
            B2, wbf + (size_t)(wslot + 2) * 16384, pf(pb + 11), cb2);
        // spatial attention on b2 (B1)
        spat_pool<<<PIX_GRID, blk, 0, stream>>>(B1, sspat);
        spat_conv<<<PIX_GRID, blk, 0, stream>>>(sspat, pf(pb + 8), aspat);
        // ssm apply + LN + * sb -> B0 (block output, bf16)
        ssm_apply<<<PW_GRID, blk, 0, stream>>>(cb2, B1, aspat, scp, pf(pb + 15), pf(pb + 16), B0);
    };

    // block 1 (weights slots 1,2,3), block 2 (slots 4,5,6; flipped reads)
    run_block(4, 1, sc1, false);
    run_block(21, 4, sc2, true);

    // final: relu(bn(pw(flip(B0), w_out))) -> d_out (f32)
    pw_mfma<128, 1, true, true, false, true><<<PW_GRID, blk, 0, stream>>>(
        B0, wbf + 7 * 16384, pf(3), OUT);
}

// Round 4
// 925.500 us; speedup vs baseline: 4.0917x; 1.1141x over previous
//
#include <hip/hip_runtime.h>
#include <cstdint>
#include <cstddef>

#define EPSF 1e-5f

// Dims (fixed by the problem)
#define BB 8
#define CC 128
#define HH 64
#define TT 512
#define HW (HH*TT)          // 32768
#define NPIX (BB*HH*TT)     // 262144

__device__ __forceinline__ float sigf(float x) { return 1.f / (1.f + expf(-x)); }
__device__ __forceinline__ float geluf(float z) { return 0.5f * z * (1.f + erff(z * 0.70710678118654752f)); }

// bf16 <-> f32 (RNE)
__device__ __forceinline__ unsigned short f2u(float f) {
    unsigned int u = __builtin_bit_cast(unsigned int, f);
    u += 0x7fffu + ((u >> 16) & 1u);
    return (unsigned short)(u >> 16);
}
__device__ __forceinline__ float u2f(unsigned short s) {
    return __builtin_bit_cast(float, (unsigned int)s << 16);
}

typedef __attribute__((ext_vector_type(8))) short bf16x8;
typedef __attribute__((ext_vector_type(4))) float f32x4;

// ---------------------------------------------------------------------------
// Weight prep: convert 8 pw weight matrices f32 -> bf16 into slots of 16384.
// slot0: w_in (8192 used), 1:b1_pwa 2:b1_pwb 3:b1_d1p 4:b2_pwa 5:b2_pwb
// 6:b2_d1p 7:w_out
// ---------------------------------------------------------------------------
__global__ __launch_bounds__(256) void prep_weights(const float* __restrict__ s0,
                                                    const float* __restrict__ s1,
                                                    const float* __restrict__ s2,
                                                    const float* __restrict__ s3,
                                                    const float* __restrict__ s4,
                                                    const float* __restrict__ s5,
                                                    const float* __restrict__ s6,
                                                    const float* __restrict__ s7,
                                                    unsigned short* __restrict__ wbf)
{
    int gid = blockIdx.x * 256 + threadIdx.x;     // 0..131071
    int slot = gid >> 14, off = gid & 16383;
    const float* srcs[8] = {s0, s1, s2, s3, s4, s5, s6, s7};
    float v = 0.f;
    if (slot != 0 || off < 8192) v = srcs[slot][off];
    wbf[gid] = f2u(v);
}

// ---------------------------------------------------------------------------
// Pointwise conv via bf16 MFMA.  out[b,o,h,t] = act(bn(sum_c in[b,c,h,t]*W[o,c]))
// Grid 4096 blocks (b,h,ttile), 256 threads (4 waves). Block: 128 o x 64 t.
// ---------------------------------------------------------------------------
template<int CIN, int ACT, bool FLIP, bool BN, bool INF32, bool OUTF32>
__global__ __launch_bounds__(256) void pw_mfma(const void* __restrict__ inv,
                                               const unsigned short* __restrict__ Wb,
                                               const float* __restrict__ bnp,
                                               void* __restrict__ outv)
{
    constexpr int CSTR = CIN + 8;
    constexpr int CP = CIN / 32;          // c-rows per staging thread
    __shared__ unsigned short Wl[128 * CSTR];
    __shared__ unsigned short Xl[64 * CSTR];
    __shared__ float bns[128], bnh[128];

    const int tid = threadIdx.x;
    const int bh = blockIdx.x >> 3, tt = blockIdx.x & 7;
    const int b = bh >> 6, h = bh & 63;
    const int t0 = tt << 6;

    if (BN && tid < 128) {
        float g = bnp[tid], be = bnp[CC + tid], m = bnp[2 * CC + tid], v = bnp[3 * CC + tid];
        float s = g * rsqrtf(v + EPSF);
        bns[tid] = s; bnh[tid] = be - m * s;
    }

    // ---- stage W (bf16, row-major o x c, padded rows) ----
    {
        constexpr int L = (128 * CIN) / (256 * 8);
#pragma unroll
        for (int i = 0; i < L; ++i) {
            int idx = (i * 256 + tid) * 8;
            int o = idx / CIN, c = idx % CIN;
            *(uint4*)&Wl[o * CSTR + c] = *(const uint4*)&Wb[o * CIN + c];
        }
    }
    // ---- stage X transposed: Xl[t][c] ----
    {
        const int s = tid & 7, g = tid >> 3;
        const int tl0 = s * 8;
        const int c0 = g * CP;
        unsigned short vals[CP][8];
#pragma unroll
        for (int i = 0; i < CP; ++i) {
            const size_t rowbase = ((size_t)(b * CIN + c0 + i) * HH + h) * TT;
            const int tb = FLIP ? (504 - t0 - tl0) : (t0 + tl0);
            if (INF32) {
                const float* pf32 = (const float*)inv;
                float4 u0 = *(const float4*)&pf32[rowbase + tb];
                float4 u1 = *(const float4*)&pf32[rowbase + tb + 4];
                float tmp[8] = {u0.x, u0.y, u0.z, u0.w, u1.x, u1.y, u1.z, u1.w};
#pragma unroll
                for (int j = 0; j < 8; ++j) vals[i][j] = f2u(tmp[FLIP ? 7 - j : j]);
            } else {
                const unsigned short* pb = (const unsigned short*)inv;
                unsigned short tmp[8];
                *(uint4*)tmp = *(const uint4*)&pb[rowbase + tb];
#pragma unroll
                for (int j = 0; j < 8; ++j) vals[i][j] = tmp[FLIP ? 7 - j : j];
            }
        }
#pragma unroll
        for (int j = 0; j < 8; ++j) {
            unsigned short* dst = &Xl[(tl0 + j) * CSTR + c0];
            if (CP == 4) {
                uint2 pk;
                pk.x = (unsigned)vals[0][j] | ((unsigned)vals[1][j] << 16);
                pk.y = (unsigned)vals[2][j] | ((unsigned)vals[3][j] << 16);
                *(uint2*)dst = pk;
            } else {
                *(unsigned int*)dst = (unsigned)vals[0][j] | ((unsigned)vals[1][j] << 16);
            }
        }
    }
    __syncthreads();

    // ---- MFMA compute: wave tile 32 o x 64 t ----
    const int lane = tid & 63, wv = tid >> 6;
    const int lanel = lane & 15, laneh = lane >> 4;
    const int ob = wv * 32;

    f32x4 acc[2][4];
#pragma unroll
    for (int f = 0; f < 2; ++f)
#pragma unroll
        for (int tf = 0; tf < 4; ++tf) acc[f][tf] = (f32x4){0.f, 0.f, 0.f, 0.f};

#pragma unroll
    for (int ks = 0; ks < CIN / 32; ++ks) {
        const int kb = ks * 32 + laneh * 8;
        bf16x8 a0 = *(const bf16x8*)&Wl[(ob + lanel) * CSTR + kb];
        bf16x8 a1 = *(const bf16x8*)&Wl[(ob + 16 + lanel) * CSTR + kb];
#pragma unroll
        for (int tf = 0; tf < 4; ++tf) {
            bf16x8 bb = *(const bf16x8*)&Xl[(tf * 16 + lanel) * CSTR + kb];
            acc[0][tf] = __builtin_amdgcn_mfma_f32_16x16x32_bf16(a0, bb, acc[0][tf], 0, 0, 0);
            acc[1][tf] = __builtin_amdgcn_mfma_f32_16x16x32_bf16(a1, bb, acc[1][tf], 0, 0, 0);
        }
    }

    // ---- epilogue: BN + act + store (D: row=(lane>>4)*4+r, col=lane&15) ----
    const size_t obase = ((size_t)(b * CC) * HH + h) * TT;
#pragma unroll
    for (int f = 0; f < 2; ++f) {
#pragma unroll
        for (int r = 0; r < 4; ++r) {
            const int row = ob + f * 16 + laneh * 4 + r;
            const float s = BN ? bns[row] : 1.f;
            const float sh = BN ? bnh[row] : 0.f;
#pragma unroll
            for (int tf = 0; tf < 4; ++tf) {
                float v = acc[f][tf][r] * s + sh;
                if (ACT == 1) v = fmaxf(v, 0.f);
                if (ACT == 2) v = sigf(v);
                size_t oidx = obase + (size_t)row * HW + t0 + tf * 16 + lanel;
                if (OUTF32) ((float*)outv)[oidx] = v;
                else ((unsigned short*)outv)[oidx] = f2u(v);
            }
        }
    }
}

// ---------------------------------------------------------------------------
// Depthwise 5x5 'same' conv (bf16 in/out, f32 compute), dual weight sets.
// Register-blocked: 32h x 64t tile per block; wave w owns 8 h-rows, lane = t.
// Per thread: 8 outputs x 2 branches; per dj reads a 12-row column slice
// (lane-consecutive -> 2 lanes/bank = conflict-free). 7.5 LDS reads/output
// vs 25 in the naive version (was LDS-issue-bound at 157us).
// Grid: BB*CC*2*8 = 16384 blocks, 256 threads.
// ---------------------------------------------------------------------------
template<bool FLIP>
__global__ __launch_bounds__(256) void dw5x5_dual(const unsigned short* __restrict__ in,
                                                  const float* __restrict__ wa,
                                                  const float* __restrict__ wb,
                                                  unsigned short* __restrict__ oa,
                                                  unsigned short* __restrict__ ob)
{
    __shared__ float tile[36][68];
    __shared__ float wla[25], wlb[25];
    const int tid = threadIdx.x;
    const int bc = blockIdx.x >> 4;
    const int tl4 = blockIdx.x & 15;
    const int ht = tl4 >> 3, tt = tl4 & 7;
    const int h0 = ht << 5, t0 = tt << 6;
    const int c = bc & (CC - 1);
    const unsigned short* base = in + (size_t)bc * HW;

    if (tid < 25) { wla[tid] = wa[c * 25 + tid]; wlb[tid] = wb[c * 25 + tid]; }
    for (int idx = tid; idx < 36 * 68; idx += 256) {
        int hl = idx / 68, tl = idx % 68;
        int hh = h0 + hl - 2, t2 = t0 + tl - 2;
        float v = 0.f;
        if (hh >= 0 && hh < HH && t2 >= 0 && t2 < TT)
            v = u2f(base[hh * TT + (FLIP ? (TT - 1) - t2 : t2)]);
        tile[hl][tl] = v;
    }
    __syncthreads();

    const int w = tid >> 6, lane = tid & 63;
    const int r0 = w * 8;

    float sa[8], sb[8];
#pragma unroll
    for (int o = 0; o < 8; ++o) { sa[o] = 0.f; sb[o] = 0.f; }

#pragma unroll
    for (int dj = 0; dj < 5; ++dj) {
        float val[12];
#pragma unroll
        for (int k = 0; k < 12; ++k) val[k] = tile[r0 + k][lane + dj];
#pragma unroll
        for (int di = 0; di < 5; ++di) {
            const float wva = wla[di * 5 + dj], wvb = wlb[di * 5 + dj];
#pragma unroll
            for (int o = 0; o < 8; ++o) {
                sa[o] += val[o + di] * wva;
                sb[o] += val[o + di] * wvb;
            }
        }
    }

    const size_t obase = (size_t)bc * HW + (size_t)(h0 + r0) * TT + t0 + lane;
#pragma unroll
    for (int o = 0; o < 8; ++o) {
        oa[obase + (size_t)o * TT] = f2u(sa[o]);
        ob[obase + (size_t)o * TT] = f2u(sb[o]);
    }
}

// ---------------------------------------------------------------------------
// Channel pooling (bf16 in): per (b,c) mean & max. Grid 1024 x 256.
// ---------------------------------------------------------------------------
__global__ __launch_bounds__(256) void chan_pool(const unsigned short* __restrict__ in,
                                                 float* __restrict__ pavg,
                                                 float* __restrict__ pmax)
{
    __shared__ float ssum[256], smax[256];
    const int bc = blockIdx.x, tid = threadIdx.x;
    const uint4* p4 = (const uint4*)(in + (size_t)bc * HW);
    float s = 0.f, m = -3.4e38f;
    for (int i = tid; i < HW / 8; i += 256) {
        uint4 u = p4[i];
        unsigned w[4] = {u.x, u.y, u.z, u.w};
#pragma unroll
        for (int k = 0; k < 4; ++k) {
            float f0 = __builtin_bit_cast(float, w[k] << 16);
            float f1 = __builtin_bit_cast(float, w[k] & 0xffff0000u);
            s += f0 + f1; m = fmaxf(m, fmaxf(f0, f1));
        }
    }
    ssum[tid] = s; smax[tid] = m;
    __syncthreads();
    for (int w2 = 128; w2 > 0; w2 >>= 1) {
        if (tid < w2) { ssum[tid] += ssum[tid + w2]; smax[tid] = fmaxf(smax[tid], smax[tid + w2]); }
        __syncthreads();
    }
    if (tid == 0) { pavg[bc] = ssum[0] * (1.f / (float)HW); pmax[bc] = smax[0]; }
}

// ---------------------------------------------------------------------------
// Channel-attention MLP (f32 small). One block, 256 threads.
// ---------------------------------------------------------------------------
__global__ __launch_bounds__(256) void chan_mlp(const float* __restrict__ pavg,
                                                const float* __restrict__ pmax,
                                                const float* __restrict__ w1,
                                                const float* __restrict__ w2,
                                                float* __restrict__ a)
{
    __shared__ float ua[8][128], um[8][128], hida[8][8], hidm[8][8];
    const int tid = threadIdx.x;
    for (int idx = tid; idx < 1024; idx += 256) {
        ua[idx >> 7][idx & 127] = pavg[idx];
        um[idx >> 7][idx & 127] = pmax[idx];
    }
    __syncthreads();
    if (tid < 128) {
        int b = tid >> 4, m = (tid >> 1) & 7, path = tid & 1;
        const float* u = path ? um[b] : ua[b];
        float acc = 0.f;
#pragma unroll
        for (int cc2 = 0; cc2 < 128; ++cc2) acc += u[cc2] * w1[m * 128 + cc2];
        acc = fmaxf(acc, 0.f);
        if (path) hidm[b][m] = acc; else hida[b][m] = acc;
    }
    __syncthreads();
    for (int idx = tid; idx < 1024; idx += 256) {
        int b = idx >> 7, cc2 = idx & 127;
        float acc = 0.f;
#pragma unroll
        for (int m = 0; m < 8; ++m) acc += (hida[b][m] + hidm[b][m]) * w2[cc2 * 8 + m];
        a[idx] = sigf(acc);
    }
}

// ---------------------------------------------------------------------------
// cb = b1^2 * a[b,c] then depthwise 1x3 conv along t (bf16 in/out).
// Grid 16384 x 256; thread: 8 consecutive t.
// ---------------------------------------------------------------------------
__global__ __launch_bounds__(256) void cb_dw1x3(const unsigned short* __restrict__ b1,
                                                const float* __restrict__ ach,
                                                const float* __restrict__ w,
                                                unsigned short* __restrict__ out)
{
    const int gid = blockIdx.x * 256 + threadIdx.x;
    const int t0 = (gid & 63) << 3;
    const int r = gid >> 6;
    const int h = r & 63;
    const int bc = r >> 6;
    const int c = bc & 127;
    const unsigned short* p = b1 + ((size_t)bc * HH + h) * TT;
    const float av = ach[bc];
    const float w0 = w[c * 3 + 0], w1v = w[c * 3 + 1], w2v = w[c * 3 + 2];
    unsigned short raw[8];
    *(uint4*)raw = *(const uint4*)&p[t0];
    float cb[10];
    { float l = (t0 > 0) ? u2f(p[t0 - 1]) : 0.f; cb[0] = (t0 > 0) ? l * l * av : 0.f; }
    { float rr = (t0 + 8 < TT) ? u2f(p[t0 + 8]) : 0.f; cb[9] = (t0 + 8 < TT) ? rr * rr * av : 0.f; }
#pragma unroll
    for (int j = 0; j < 8; ++j) { float x = u2f(raw[j]); cb[j + 1] = x * x * av; }
    unsigned short o8[8];
#pragma unroll
    for (int j = 0; j < 8; ++j) o8[j] = f2u(cb[j] * w0 + cb[j + 1] * w1v + cb[j + 2] * w2v);
    *(uint4*)&out[((size_t)bc * HH + h) * TT + t0] = *(uint4*)o8;
}

// ---------------------------------------------------------------------------
// Spatial pooling (bf16 in): per-pixel mean & max over channels. Grid 1024x256.
// ---------------------------------------------------------------------------
__global__ __launch_bounds__(256) void spat_pool(const unsigned short* __restrict__ in,
                                                 float* __restrict__ s)
{
    const int pix = blockIdx.x * 256 + threadIdx.x;
    const int t = pix & 511, h = (pix >> 9) & 63, b = pix >> 15;
    const unsigned short* p = in + ((size_t)b * CC * HH + h) * TT + t;
    float sum = 0.f, mx = -3.4e38f;
#pragma unroll 8
    for (int c = 0; c < CC; ++c) {
        float v = u2f(p[(size_t)c * HW]);
        sum += v; mx = fmaxf(mx, v);
    }
    const int sp = h * TT + t;
    s[((size_t)b * 2) * HW + sp] = sum * (1.f / (float)CC);
    s[((size_t)b * 2 + 1) * HW + sp] = mx;
}

// ---------------------------------------------------------------------------
// 7x7 conv on 2-ch pooled map + sigmoid (f32). Grid 1024x256.
// ---------------------------------------------------------------------------
__global__ __launch_bounds__(256) void spat_conv(const float* __restrict__ s,
                                                 const float* __restrict__ w,
                                                 float* __restrict__ a)
{
    __shared__ float wl[98];
    const int tid = threadIdx.x;
    if (tid < 98) wl[tid] = w[tid];
    __syncthreads();
    const int pix = blockIdx.x * 256 + tid;
    const int t = pix & 511, h = (pix >> 9) & 63, b = pix >> 15;
    float acc = 0.f;
#pragma unroll
    for (int ch = 0; ch < 2; ++ch) {
        const float* sp = s + ((size_t)b * 2 + ch) * HW;
#pragma unroll
        for (int di = 0; di < 7; ++di) {
            int hh = h + di - 3;
            if (hh < 0 || hh >= HH) continue;
#pragma unroll
            for (int dj = 0; dj < 7; ++dj) {
                int t2 = t + dj - 3;
                if (t2 < 0 || t2 >= TT) continue;
                acc += sp[hh * TT + t2] * wl[ch * 49 + di * 7 + dj];
            }
        }
    }
    a[pix] = sigf(acc);
}

// ---------------------------------------------------------------------------
// SSM scan (input-independent): sc[c][t] for both blocks. f32.
// ---------------------------------------------------------------------------
__global__ __launch_bounds__(512) void scan_kernel(const float* __restrict__ A1,
                                                   const float* __restrict__ B1,
                                                   const float* __restrict__ C1,
                                                   const float* __restrict__ A2,
                                                   const float* __restrict__ B2,
                                                   const float* __restrict__ C2,
                                                   float* __restrict__ sc1,
                                                   float* __restrict__ sc2,
                                                   float* __restrict__ Sws)
{
    const float* A = blockIdx.x ? A2 : A1;
    const float* Bv = blockIdx.x ? B2 : B1;
    const float* Cm = blockIdx.x ? C2 : C1;
    float* sc = blockIdx.x ? sc2 : sc1;
    float* Sg = Sws + (size_t)blockIdx.x * (TT * 32);

    __shared__ float M[32][33];
    __shared__ float P[32][33];
    __shared__ float Q[32][33];
    __shared__ float L64[32];
    __shared__ float Eq[8][32];
    __shared__ float Cs[32][128];

    const int tid = threadIdx.x;
    const int wave = tid >> 6, lane = tid & 63;

    for (int idx = tid; idx < 1024; idx += 512) {
        int j = idx >> 5, i = idx & 31;
        float v = A[i * 32 + j];
        M[j][i] = v; P[j][i] = v;
    }
    for (int idx = tid; idx < 4096; idx += 512) Cs[idx >> 7][idx & 127] = Cm[idx];
    __syncthreads();

    for (int sq = 0; sq < 6; ++sq) {
        for (int idx = tid; idx < 1024; idx += 512) {
            int r = idx >> 5, c2 = idx & 31;
            float acc = 0.f;
#pragma unroll
            for (int k = 0; k < 32; ++k) acc += P[r][k] * P[k][c2];
            Q[r][c2] = acc;
        }
        __syncthreads();
        for (int idx = tid; idx < 1024; idx += 512) {
            int r = idx >> 5, c2 = idx & 31;
            P[r][c2] = Q[r][c2];
        }
        __syncthreads();
    }

    if (wave == 0) {
        float bval = (lane < 32) ? Bv[lane] : 0.f;
        float z = 0.f;
        for (int r = 0; r < 64; ++r) {
            float zn = bval;
#pragma unroll
            for (int j = 0; j < 32; ++j) zn += __shfl(z, j, 64) * M[j][lane & 31];
            z = zn;
        }
        if (lane < 32) L64[lane] = z;
    }
    __syncthreads();

    if (wave == 0) {
        float e = 0.f;
        if (lane < 32) Eq[0][lane] = 0.f;
        for (int q = 1; q < 8; ++q) {
            float en = (lane < 32) ? L64[lane] : 0.f;
#pragma unroll
            for (int j = 0; j < 32; ++j) en += __shfl(e, j, 64) * P[j][lane & 31];
            e = en;
            if (lane < 32) Eq[q][lane] = e;
        }
    }
    __syncthreads();

    {
        float bval = (lane < 32) ? Bv[lane] : 0.f;
        float z = (lane < 32) ? Eq[wave][lane] : 0.f;
        for (int r = 0; r < 64; ++r) {
            float zn = bval;
#pragma unroll
            for (int j = 0; j < 32; ++j) zn += __shfl(z, j, 64) * M[j][lane & 31];
            z = zn;
            if (lane < 32) Sg[(wave * 64 + r) * 32 + lane] = z;
        }
    }
    __syncthreads();

    {
        float sreg[32];
#pragma unroll
        for (int j = 0; j < 32; ++j) sreg[j] = Sg[tid * 32 + j];
        for (int c = 0; c < 128; ++c) {
            float acc = 0.f;
#pragma unroll
            for (int j = 0; j < 32; ++j) acc += sreg[j] * Cs[j][c];
            sc[c * TT + tid] = acc;
        }
    }
}

// ---------------------------------------------------------------------------
// SSM apply + LayerNorm + spatial-branch multiply (LDS-tiled).
// cb2 f32, b2 bf16, out bf16. Grid 4096 x 256.
// ---------------------------------------------------------------------------
__global__ __launch_bounds__(256) void ssm_apply(const float* __restrict__ cb2,
                                                 const unsigned short* __restrict__ b2,
                                                 const float* __restrict__ aspat,
                                                 const float* __restrict__ sc,
                                                 const float* __restrict__ Dv,
                                                 const float* __restrict__ ln,
                                                 unsigned short* __restrict__ out)
{
    __shared__ float tile[128][64];
    __shared__ float psum[4][64], psq[4][64];
    __shared__ float smu[64], srstd[64];
    __shared__ float sas[64];
    const int tid = threadIdx.x;
    const int bid = blockIdx.x;
    const int ttile = bid & 7, h = (bid >> 3) & 63, b = bid >> 9;
    const int t0 = ttile << 6;
    const int tl = tid & 63, g = tid >> 6;
    const size_t base = (size_t)b * CC * HW + (size_t)h * TT + t0;

    if (tid < 64) sas[tid] = aspat[((size_t)b * HH + h) * TT + t0 + tid];

    float s = 0.f, sq = 0.f;
#pragma unroll
    for (int i = 0; i < 32; ++i) {
        int c = 4 * i + g;
        float x = cb2[base + (size_t)c * HW + tl];
        float z = sc[c * TT + t0 + tl] + x * Dv[c];
        float o = x + geluf(z);
        tile[c][tl] = o;
        s += o; sq += o * o;
    }
    psum[g][tl] = s; psq[g][tl] = sq;
    __syncthreads();
    if (tid < 64) {
        float su = psum[0][tid] + psum[1][tid] + psum[2][tid] + psum[3][tid];
        float qu = psq[0][tid] + psq[1][tid] + psq[2][tid] + psq[3][tid];
        float mu = su * (1.f / 128.f);
        float var = qu * (1.f / 128.f) - mu * mu;
        smu[tid] = mu;
        srstd[tid] = rsqrtf(var + EPSF);
    }
    __syncthreads();

    const float mu = smu[tl], rstd = srstd[tl], asv = sas[tl];
#pragma unroll
    for (int i = 0; i < 32; ++i) {
        int c = 4 * i + g;
        float lnw = ln[c], lnb = ln[CC + c];
        float val = (tile[c][tl] - mu) * rstd * lnw + lnb;
        float bv = u2f(b2[base + (size_t)c * HW + tl]);
        float sb = sigf(bv * bv * asv);
        out[base + (size_t)c * HW + tl] = f2u(val * sb);
    }
}

// ---------------------------------------------------------------------------
// Host-side launch
// ---------------------------------------------------------------------------
extern "C" void kernel_launch(void* const* d_in, const int* in_sizes, int n_in,
                              void* d_out, int out_size, void* d_ws, size_t ws_size,
                              hipStream_t stream)
{
    (void)in_sizes; (void)n_in; (void)out_size; (void)ws_size;

    auto pf = [&](int i) { return (const float*)d_in[i]; };

    const float* x = pf(0);

    const size_t NT = (size_t)BB * CC * HH * TT;      // 33554432
    unsigned short* B0 = (unsigned short*)d_ws;
    unsigned short* B1 = B0 + NT;
    unsigned short* B2 = B1 + NT;
    unsigned short* wbf = B2 + NT;                    // 8 x 16384 bf16
    float* sc1 = (float*)(wbf + 8 * 16384);
    float* sc2 = sc1 + CC * TT;
    float* Sws = sc2 + CC * TT;                       // 2*512*32
    float* pavg = Sws + 2 * TT * 32;
    float* pmax = pavg + BB * CC;
    float* achan = pmax + BB * CC;
    float* sspat = achan + BB * CC;                   // 8*2*32768
    float* aspat = sspat + (size_t)BB * 2 * HW;       // 262144
    float* cb2 = (float*)d_out;                       // f32 scratch until final
    float* OUT = (float*)d_out;

    const dim3 blk(256);
    const int PW_GRID = 4096;
    const int DW_GRID = 16384;
    const int PIX_GRID = NPIX / 256;                  // 1024
    const int D1_GRID = 16384;

    prep_weights<<<512, blk, 0, stream>>>(pf(1), pf(5), pf(8), pf(14),
                                          pf(22), pf(25), pf(31), pf(2), wbf);
    scan_kernel<<<2, 512, 0, stream>>>(pf(16), pf(17), pf(18), pf(33), pf(34), pf(35),
                                       sc1, sc2, Sws);

    // stem: x(f32) -> B0 (bf16)
    pw_mfma<64, 0, false, false, true, false><<<PW_GRID, blk, 0, stream>>>(x, wbf + 0, nullptr, B0);

    auto run_block = [&](int pb, int wslot, const float* scp, bool flip) {
        // dw5x5 both branches: B0 -> B1(Da), B2(Db)
        if (flip)
            dw5x5_dual<true><<<DW_GRID, blk, 0, stream>>>(B0, pf(pb + 0), pf(pb + 3), B1, B2);
        else
            dw5x5_dual<false><<<DW_GRID, blk, 0, stream>>>(B0, pf(pb + 0), pf(pb + 3), B1, B2);
        // b1 = relu(bn(pw(Da))) -> B0 ; b2 = relu(bn(pw(Db))) -> B1
        pw_mfma<128, 1, false, true, false, false><<<PW_GRID, blk, 0, stream>>>(
            B1, wbf + (size_t)wslot * 16384, pf(pb + 2), B0);
        pw_mfma<128, 1, false, true, false, false><<<PW_GRID, blk, 0, stream>>>(
            B2, wbf + (size_t)(wslot + 1) * 16384, pf(pb + 5), B1);
        // channel attention on b1 (B0)
        chan_pool<<<BB * CC, blk, 0, stream>>>(B0, pavg, pmax);
        chan_mlp<<<1, blk, 0, stream>>>(pavg, pmax, pf(pb + 6), pf(pb + 7), achan);
        // cb chain: (b1^2*a) -> dw1x3 -> B2 ; pw+bn+sigmoid -> cb2 (f32, d_out)
        cb_dw1x3<<<D1_GRID, blk, 0, stream>>>(B0, achan, pf(pb + 9), B2);
        pw_mfma<128, 2, false, true, false, true><<<PW_GRID, blk, 0, stream>>>(
            B2, wbf + (size_t)(wslot + 2) * 16384, pf(pb + 11), cb2);
        // spatial attention on b2 (B1)
        spat_pool<<<PIX_GRID, blk, 0, stream>>>(B1, sspat);
        spat_conv<<<PIX_GRID, blk, 0, stream>>>(sspat, pf(pb + 8), aspat);
        // ssm apply + LN + * sb -> B0 (block output, bf16)
        ssm_apply<<<PW_GRID, blk, 0, stream>>>(cb2, B1, aspat, scp, pf(pb + 15), pf(pb + 16), B0);
    };

    // block 1 (weights slots 1,2,3), block 2 (slots 4,5,6; flipped reads)
    run_block(4, 1, sc1, false);
    run_block(21, 4, sc2, true);

    // final: relu(bn(pw(flip(B0), w_out))) -> d_out (f32)
    pw_mfma<128, 1, true, true, false, true><<<PW_GRID, blk, 0, stream>>>(
        B0, wbf + 7 * 16384, pf(3), OUT);
}

// Round 5
// 792.849 us; speedup vs baseline: 4.7763x; 1.1673x over previous
//
#include <hip/hip_runtime.h>
#include <cstdint>
#include <cstddef>

#define EPSF 1e-5f

// Dims (fixed by the problem)
#define BB 8
#define CC 128
#define HH 64
#define TT 512
#define HW (HH*TT)          // 32768
#define NPIX (BB*HH*TT)     // 262144

__device__ __forceinline__ float sigf(float x) { return 1.f / (1.f + expf(-x)); }
__device__ __forceinline__ float geluf(float z) { return 0.5f * z * (1.f + erff(z * 0.70710678118654752f)); }

// bf16 <-> f32 (RNE)
__device__ __forceinline__ unsigned short f2u(float f) {
    unsigned int u = __builtin_bit_cast(unsigned int, f);
    u += 0x7fffu + ((u >> 16) & 1u);
    return (unsigned short)(u >> 16);
}
__device__ __forceinline__ float u2f(unsigned short s) {
    return __builtin_bit_cast(float, (unsigned int)s << 16);
}

typedef __attribute__((ext_vector_type(8))) short bf16x8;
typedef __attribute__((ext_vector_type(4))) float f32x4;

// ---------------------------------------------------------------------------
// Weight prep: convert 8 pw weight matrices f32 -> bf16 into slots of 16384.
// slot0: w_in (8192 used), 1:b1_pwa 2:b1_pwb 3:b1_d1p 4:b2_pwa 5:b2_pwb
// 6:b2_d1p 7:w_out
// ---------------------------------------------------------------------------
__global__ __launch_bounds__(256) void prep_weights(const float* __restrict__ s0,
                                                    const float* __restrict__ s1,
                                                    const float* __restrict__ s2,
                                                    const float* __restrict__ s3,
                                                    const float* __restrict__ s4,
                                                    const float* __restrict__ s5,
                                                    const float* __restrict__ s6,
                                                    const float* __restrict__ s7,
                                                    unsigned short* __restrict__ wbf)
{
    int gid = blockIdx.x * 256 + threadIdx.x;     // 0..131071
    int slot = gid >> 14, off = gid & 16383;
    const float* srcs[8] = {s0, s1, s2, s3, s4, s5, s6, s7};
    float v = 0.f;
    if (slot != 0 || off < 8192) v = srcs[slot][off];
    wbf[gid] = f2u(v);
}

// ---------------------------------------------------------------------------
// Pointwise conv via bf16 MFMA.  out[b,o,h,t] = act(bn(sum_c in[b,c,h,t]*W[o,c]))
// Grid 4096 blocks (b,h,ttile), 256 threads (4 waves). Block: 128 o x 64 t.
// ---------------------------------------------------------------------------
template<int CIN, int ACT, bool FLIP, bool BN, bool INF32, bool OUTF32>
__global__ __launch_bounds__(256) void pw_mfma(const void* __restrict__ inv,
                                               const unsigned short* __restrict__ Wb,
                                               const float* __restrict__ bnp,
                                               void* __restrict__ outv)
{
    constexpr int CSTR = CIN + 8;
    constexpr int CP = CIN / 32;          // c-rows per staging thread
    __shared__ unsigned short Wl[128 * CSTR];
    __shared__ unsigned short Xl[64 * CSTR];
    __shared__ float bns[128], bnh[128];

    const int tid = threadIdx.x;
    const int bh = blockIdx.x >> 3, tt = blockIdx.x & 7;
    const int b = bh >> 6, h = bh & 63;
    const int t0 = tt << 6;

    if (BN && tid < 128) {
        float g = bnp[tid], be = bnp[CC + tid], m = bnp[2 * CC + tid], v = bnp[3 * CC + tid];
        float s = g * rsqrtf(v + EPSF);
        bns[tid] = s; bnh[tid] = be - m * s;
    }

    // ---- stage W (bf16, row-major o x c, padded rows) ----
    {
        constexpr int L = (128 * CIN) / (256 * 8);
#pragma unroll
        for (int i = 0; i < L; ++i) {
            int idx = (i * 256 + tid) * 8;
            int o = idx / CIN, c = idx % CIN;
            *(uint4*)&Wl[o * CSTR + c] = *(const uint4*)&Wb[o * CIN + c];
        }
    }
    // ---- stage X transposed: Xl[t][c] ----
    {
        const int s = tid & 7, g = tid >> 3;
        const int tl0 = s * 8;
        const int c0 = g * CP;
        unsigned short vals[CP][8];
#pragma unroll
        for (int i = 0; i < CP; ++i) {
            const size_t rowbase = ((size_t)(b * CIN + c0 + i) * HH + h) * TT;
            const int tb = FLIP ? (504 - t0 - tl0) : (t0 + tl0);
            if (INF32) {
                const float* pf32 = (const float*)inv;
                float4 u0 = *(const float4*)&pf32[rowbase + tb];
                float4 u1 = *(const float4*)&pf32[rowbase + tb + 4];
                float tmp[8] = {u0.x, u0.y, u0.z, u0.w, u1.x, u1.y, u1.z, u1.w};
#pragma unroll
                for (int j = 0; j < 8; ++j) vals[i][j] = f2u(tmp[FLIP ? 7 - j : j]);
            } else {
                const unsigned short* pb = (const unsigned short*)inv;
                unsigned short tmp[8];
                *(uint4*)tmp = *(const uint4*)&pb[rowbase + tb];
#pragma unroll
                for (int j = 0; j < 8; ++j) vals[i][j] = tmp[FLIP ? 7 - j : j];
            }
        }
#pragma unroll
        for (int j = 0; j < 8; ++j) {
            unsigned short* dst = &Xl[(tl0 + j) * CSTR + c0];
            if (CP == 4) {
                uint2 pk;
                pk.x = (unsigned)vals[0][j] | ((unsigned)vals[1][j] << 16);
                pk.y = (unsigned)vals[2][j] | ((unsigned)vals[3][j] << 16);
                *(uint2*)dst = pk;
            } else {
                *(unsigned int*)dst = (unsigned)vals[0][j] | ((unsigned)vals[1][j] << 16);
            }
        }
    }
    __syncthreads();

    // ---- MFMA compute: wave tile 32 o x 64 t ----
    const int lane = tid & 63, wv = tid >> 6;
    const int lanel = lane & 15, laneh = lane >> 4;
    const int ob = wv * 32;

    f32x4 acc[2][4];
#pragma unroll
    for (int f = 0; f < 2; ++f)
#pragma unroll
        for (int tf = 0; tf < 4; ++tf) acc[f][tf] = (f32x4){0.f, 0.f, 0.f, 0.f};

#pragma unroll
    for (int ks = 0; ks < CIN / 32; ++ks) {
        const int kb = ks * 32 + laneh * 8;
        bf16x8 a0 = *(const bf16x8*)&Wl[(ob + lanel) * CSTR + kb];
        bf16x8 a1 = *(const bf16x8*)&Wl[(ob + 16 + lanel) * CSTR + kb];
#pragma unroll
        for (int tf = 0; tf < 4; ++tf) {
            bf16x8 bb = *(const bf16x8*)&Xl[(tf * 16 + lanel) * CSTR + kb];
            acc[0][tf] = __builtin_amdgcn_mfma_f32_16x16x32_bf16(a0, bb, acc[0][tf], 0, 0, 0);
            acc[1][tf] = __builtin_amdgcn_mfma_f32_16x16x32_bf16(a1, bb, acc[1][tf], 0, 0, 0);
        }
    }

    // ---- epilogue: BN + act + store (D: row=(lane>>4)*4+r, col=lane&15) ----
    const size_t obase = ((size_t)(b * CC) * HH + h) * TT;
#pragma unroll
    for (int f = 0; f < 2; ++f) {
#pragma unroll
        for (int r = 0; r < 4; ++r) {
            const int row = ob + f * 16 + laneh * 4 + r;
            const float s = BN ? bns[row] : 1.f;
            const float sh = BN ? bnh[row] : 0.f;
#pragma unroll
            for (int tf = 0; tf < 4; ++tf) {
                float v = acc[f][tf][r] * s + sh;
                if (ACT == 1) v = fmaxf(v, 0.f);
                if (ACT == 2) v = sigf(v);
                size_t oidx = obase + (size_t)row * HW + t0 + tf * 16 + lanel;
                if (OUTF32) ((float*)outv)[oidx] = v;
                else ((unsigned short*)outv)[oidx] = f2u(v);
            }
        }
    }
}

// ---------------------------------------------------------------------------
// FUSED: pointwise (d1p) + BN + sigmoid -> x; z = sc + x*D; o = x + gelu(z);
// LayerNorm over channels; out = LN(o) * sigmoid(b2^2 * aspat).  All in one
// kernel: the block holds all 128 channels of 64 t-columns in its MFMA accs.
// Grid 4096 (b,h,ttile), 256 threads.
// ---------------------------------------------------------------------------
__global__ __launch_bounds__(256) void pw_ssm(const unsigned short* __restrict__ inp,
                                              const unsigned short* __restrict__ Wb,
                                              const float* __restrict__ bnp,
                                              const unsigned short* __restrict__ b2t,
                                              const float* __restrict__ aspat,
                                              const float* __restrict__ sc,
                                              const float* __restrict__ Dv,
                                              const float* __restrict__ ln,
                                              unsigned short* __restrict__ outp)
{
    constexpr int CIN = 128;
    constexpr int CSTR = CIN + 8;
    __shared__ unsigned short Wl[128 * CSTR];
    __shared__ unsigned short Xl[64 * CSTR];
    __shared__ float bns[128], bnh[128];
    __shared__ float sDv[128], slnw[128], slnb[128];
    __shared__ float psum[4][64], psq[4][64];
    __shared__ float smu[64], srstd[64], sas[64];

    const int tid = threadIdx.x;
    const int bh = blockIdx.x >> 3, tt = blockIdx.x & 7;
    const int b = bh >> 6, h = bh & 63;
    const int t0 = tt << 6;

    if (tid < 128) {
        float g = bnp[tid], be = bnp[CC + tid], m = bnp[2 * CC + tid], v = bnp[3 * CC + tid];
        float s = g * rsqrtf(v + EPSF);
        bns[tid] = s; bnh[tid] = be - m * s;
        sDv[tid] = Dv[tid]; slnw[tid] = ln[tid]; slnb[tid] = ln[CC + tid];
    }
    if (tid < 64) sas[tid] = aspat[((size_t)b * HH + h) * TT + t0 + tid];

    // ---- stage W ----
#pragma unroll
    for (int i = 0; i < 8; ++i) {
        int idx = (i * 256 + tid) * 8;
        int o = idx >> 7, c = idx & 127;
        *(uint4*)&Wl[o * CSTR + c] = *(const uint4*)&Wb[o * CIN + c];
    }
    // ---- stage X transposed ----
    {
        const int s = tid & 7, g = tid >> 3;
        const int tl0 = s * 8;
        const int c0 = g * 4;
        unsigned short vals[4][8];
#pragma unroll
        for (int i = 0; i < 4; ++i) {
            const size_t rowbase = ((size_t)(b * CIN + c0 + i) * HH + h) * TT;
            *(uint4*)vals[i] = *(const uint4*)&inp[rowbase + t0 + tl0];
        }
#pragma unroll
        for (int j = 0; j < 8; ++j) {
            uint2 pk;
            pk.x = (unsigned)vals[0][j] | ((unsigned)vals[1][j] << 16);
            pk.y = (unsigned)vals[2][j] | ((unsigned)vals[3][j] << 16);
            *(uint2*)&Xl[(tl0 + j) * CSTR + c0] = pk;
        }
    }
    __syncthreads();

    const int lane = tid & 63, wv = tid >> 6;
    const int lanel = lane & 15, laneh = lane >> 4;
    const int ob = wv * 32;

    f32x4 acc[2][4];
#pragma unroll
    for (int f = 0; f < 2; ++f)
#pragma unroll
        for (int tf = 0; tf < 4; ++tf) acc[f][tf] = (f32x4){0.f, 0.f, 0.f, 0.f};

#pragma unroll
    for (int ks = 0; ks < 4; ++ks) {
        const int kb = ks * 32 + laneh * 8;
        bf16x8 a0 = *(const bf16x8*)&Wl[(ob + lanel) * CSTR + kb];
        bf16x8 a1 = *(const bf16x8*)&Wl[(ob + 16 + lanel) * CSTR + kb];
#pragma unroll
        for (int tf = 0; tf < 4; ++tf) {
            bf16x8 bb = *(const bf16x8*)&Xl[(tf * 16 + lanel) * CSTR + kb];
            acc[0][tf] = __builtin_amdgcn_mfma_f32_16x16x32_bf16(a0, bb, acc[0][tf], 0, 0, 0);
            acc[1][tf] = __builtin_amdgcn_mfma_f32_16x16x32_bf16(a1, bb, acc[1][tf], 0, 0, 0);
        }
    }

    // ---- SSM + GELU, accumulate per-column LN partials ----
    float ps[4] = {0.f, 0.f, 0.f, 0.f}, pq[4] = {0.f, 0.f, 0.f, 0.f};
#pragma unroll
    for (int f = 0; f < 2; ++f) {
#pragma unroll
        for (int r = 0; r < 4; ++r) {
            const int row = ob + f * 16 + laneh * 4 + r;
            const float s = bns[row], sh = bnh[row], dv = sDv[row];
#pragma unroll
            for (int tf = 0; tf < 4; ++tf) {
                const int col = tf * 16 + lanel;
                float x = sigf(acc[f][tf][r] * s + sh);
                float z = sc[row * TT + t0 + col] + x * dv;
                float o = x + geluf(z);
                acc[f][tf][r] = o;
                ps[tf] += o; pq[tf] += o * o;
            }
        }
    }
#pragma unroll
    for (int tf = 0; tf < 4; ++tf) {
        ps[tf] += __shfl_xor(ps[tf], 16);
        ps[tf] += __shfl_xor(ps[tf], 32);
        pq[tf] += __shfl_xor(pq[tf], 16);
        pq[tf] += __shfl_xor(pq[tf], 32);
    }
    if (laneh == 0) {
#pragma unroll
        for (int tf = 0; tf < 4; ++tf) {
            psum[wv][tf * 16 + lanel] = ps[tf];
            psq[wv][tf * 16 + lanel] = pq[tf];
        }
    }
    __syncthreads();
    if (tid < 64) {
        float su = psum[0][tid] + psum[1][tid] + psum[2][tid] + psum[3][tid];
        float qu = psq[0][tid] + psq[1][tid] + psq[2][tid] + psq[3][tid];
        float mu = su * (1.f / 128.f);
        float var = qu * (1.f / 128.f) - mu * mu;
        smu[tid] = mu; srstd[tid] = rsqrtf(var + EPSF);
    }
    __syncthreads();

    // ---- LN + spatial-branch multiply + store bf16 ----
    const size_t obase = ((size_t)(b * CC) * HH + h) * TT;
#pragma unroll
    for (int f = 0; f < 2; ++f) {
#pragma unroll
        for (int r = 0; r < 4; ++r) {
            const int row = ob + f * 16 + laneh * 4 + r;
            const float lw = slnw[row], lb = slnb[row];
#pragma unroll
            for (int tf = 0; tf < 4; ++tf) {
                const int col = tf * 16 + lanel;
                float val = (acc[f][tf][r] - smu[col]) * srstd[col] * lw + lb;
                float bv = u2f(b2t[obase + (size_t)row * HW + t0 + col]);
                float sb = sigf(bv * bv * sas[col]);
                outp[obase + (size_t)row * HW + t0 + col] = f2u(val * sb);
            }
        }
    }
}

// ---------------------------------------------------------------------------
// Depthwise 5x5 'same' conv (bf16 in/out, f32 compute), dual weight sets.
// Register-blocked: 32h x 64t tile per block; wave owns 8 h-rows, lane = t.
// Grid: BB*CC*2*8 = 16384 blocks, 256 threads.
// ---------------------------------------------------------------------------
template<bool FLIP>
__global__ __launch_bounds__(256) void dw5x5_dual(const unsigned short* __restrict__ in,
                                                  const float* __restrict__ wa,
                                                  const float* __restrict__ wb,
                                                  unsigned short* __restrict__ oa,
                                                  unsigned short* __restrict__ ob)
{
    __shared__ float tile[36][68];
    __shared__ float wla[25], wlb[25];
    const int tid = threadIdx.x;
    const int bc = blockIdx.x >> 4;
    const int tl4 = blockIdx.x & 15;
    const int ht = tl4 >> 3, tt = tl4 & 7;
    const int h0 = ht << 5, t0 = tt << 6;
    const int c = bc & (CC - 1);
    const unsigned short* base = in + (size_t)bc * HW;

    if (tid < 25) { wla[tid] = wa[c * 25 + tid]; wlb[tid] = wb[c * 25 + tid]; }
    for (int idx = tid; idx < 36 * 68; idx += 256) {
        int hl = idx / 68, tl = idx % 68;
        int hh = h0 + hl - 2, t2 = t0 + tl - 2;
        float v = 0.f;
        if (hh >= 0 && hh < HH && t2 >= 0 && t2 < TT)
            v = u2f(base[hh * TT + (FLIP ? (TT - 1) - t2 : t2)]);
        tile[hl][tl] = v;
    }
    __syncthreads();

    const int w = tid >> 6, lane = tid & 63;
    const int r0 = w * 8;

    float sa[8], sb[8];
#pragma unroll
    for (int o = 0; o < 8; ++o) { sa[o] = 0.f; sb[o] = 0.f; }

#pragma unroll
    for (int dj = 0; dj < 5; ++dj) {
        float val[12];
#pragma unroll
        for (int k = 0; k < 12; ++k) val[k] = tile[r0 + k][lane + dj];
#pragma unroll
        for (int di = 0; di < 5; ++di) {
            const float wva = wla[di * 5 + dj], wvb = wlb[di * 5 + dj];
#pragma unroll
            for (int o = 0; o < 8; ++o) {
                sa[o] += val[o + di] * wva;
                sb[o] += val[o + di] * wvb;
            }
        }
    }

    const size_t obase = (size_t)bc * HW + (size_t)(h0 + r0) * TT + t0 + lane;
#pragma unroll
    for (int o = 0; o < 8; ++o) {
        oa[obase + (size_t)o * TT] = f2u(sa[o]);
        ob[obase + (size_t)o * TT] = f2u(sb[o]);
    }
}

// ---------------------------------------------------------------------------
// Channel pooling (bf16 in): per (b,c) mean & max. Grid 1024 x 256.
// ---------------------------------------------------------------------------
__global__ __launch_bounds__(256) void chan_pool(const unsigned short* __restrict__ in,
                                                 float* __restrict__ pavg,
                                                 float* __restrict__ pmax)
{
    __shared__ float ssum[256], smax[256];
    const int bc = blockIdx.x, tid = threadIdx.x;
    const uint4* p4 = (const uint4*)(in + (size_t)bc * HW);
    float s = 0.f, m = -3.4e38f;
    for (int i = tid; i < HW / 8; i += 256) {
        uint4 u = p4[i];
        unsigned w[4] = {u.x, u.y, u.z, u.w};
#pragma unroll
        for (int k = 0; k < 4; ++k) {
            float f0 = __builtin_bit_cast(float, w[k] << 16);
            float f1 = __builtin_bit_cast(float, w[k] & 0xffff0000u);
            s += f0 + f1; m = fmaxf(m, fmaxf(f0, f1));
        }
    }
    ssum[tid] = s; smax[tid] = m;
    __syncthreads();
    for (int w2 = 128; w2 > 0; w2 >>= 1) {
        if (tid < w2) { ssum[tid] += ssum[tid + w2]; smax[tid] = fmaxf(smax[tid], smax[tid + w2]); }
        __syncthreads();
    }
    if (tid == 0) { pavg[bc] = ssum[0] * (1.f / (float)HW); pmax[bc] = smax[0]; }
}

// ---------------------------------------------------------------------------
// Channel-attention MLP (f32 small). One block, 256 threads.
// ---------------------------------------------------------------------------
__global__ __launch_bounds__(256) void chan_mlp(const float* __restrict__ pavg,
                                                const float* __restrict__ pmax,
                                                const float* __restrict__ w1,
                                                const float* __restrict__ w2,
                                                float* __restrict__ a)
{
    __shared__ float ua[8][128], um[8][128], hida[8][8], hidm[8][8];
    const int tid = threadIdx.x;
    for (int idx = tid; idx < 1024; idx += 256) {
        ua[idx >> 7][idx & 127] = pavg[idx];
        um[idx >> 7][idx & 127] = pmax[idx];
    }
    __syncthreads();
    if (tid < 128) {
        int b = tid >> 4, m = (tid >> 1) & 7, path = tid & 1;
        const float* u = path ? um[b] : ua[b];
        float acc = 0.f;
#pragma unroll
        for (int cc2 = 0; cc2 < 128; ++cc2) acc += u[cc2] * w1[m * 128 + cc2];
        acc = fmaxf(acc, 0.f);
        if (path) hidm[b][m] = acc; else hida[b][m] = acc;
    }
    __syncthreads();
    for (int idx = tid; idx < 1024; idx += 256) {
        int b = idx >> 7, cc2 = idx & 127;
        float acc = 0.f;
#pragma unroll
        for (int m = 0; m < 8; ++m) acc += (hida[b][m] + hidm[b][m]) * w2[cc2 * 8 + m];
        a[idx] = sigf(acc);
    }
}

// ---------------------------------------------------------------------------
// cb = b1^2 * a[b,c] then depthwise 1x3 conv along t (bf16 in/out).
// Grid 16384 x 256; thread: 8 consecutive t.
// ---------------------------------------------------------------------------
__global__ __launch_bounds__(256) void cb_dw1x3(const unsigned short* __restrict__ b1,
                                                const float* __restrict__ ach,
                                                const float* __restrict__ w,
                                                unsigned short* __restrict__ out)
{
    const int gid = blockIdx.x * 256 + threadIdx.x;
    const int t0 = (gid & 63) << 3;
    const int r = gid >> 6;
    const int h = r & 63;
    const int bc = r >> 6;
    const int c = bc & 127;
    const unsigned short* p = b1 + ((size_t)bc * HH + h) * TT;
    const float av = ach[bc];
    const float w0 = w[c * 3 + 0], w1v = w[c * 3 + 1], w2v = w[c * 3 + 2];
    unsigned short raw[8];
    *(uint4*)raw = *(const uint4*)&p[t0];
    float cb[10];
    { float l = (t0 > 0) ? u2f(p[t0 - 1]) : 0.f; cb[0] = (t0 > 0) ? l * l * av : 0.f; }
    { float rr = (t0 + 8 < TT) ? u2f(p[t0 + 8]) : 0.f; cb[9] = (t0 + 8 < TT) ? rr * rr * av : 0.f; }
#pragma unroll
    for (int j = 0; j < 8; ++j) { float x = u2f(raw[j]); cb[j + 1] = x * x * av; }
    unsigned short o8[8];
#pragma unroll
    for (int j = 0; j < 8; ++j) o8[j] = f2u(cb[j] * w0 + cb[j + 1] * w1v + cb[j + 2] * w2v);
    *(uint4*)&out[((size_t)bc * HH + h) * TT + t0] = *(uint4*)o8;
}

// ---------------------------------------------------------------------------
// Spatial pooling (bf16 in): per-pixel mean & max over channels. Grid 1024x256.
// ---------------------------------------------------------------------------
__global__ __launch_bounds__(256) void spat_pool(const unsigned short* __restrict__ in,
                                                 float* __restrict__ s)
{
    const int pix = blockIdx.x * 256 + threadIdx.x;
    const int t = pix & 511, h = (pix >> 9) & 63, b = pix >> 15;
    const unsigned short* p = in + ((size_t)b * CC * HH + h) * TT + t;
    float sum = 0.f, mx = -3.4e38f;
#pragma unroll 8
    for (int c = 0; c < CC; ++c) {
        float v = u2f(p[(size_t)c * HW]);
        sum += v; mx = fmaxf(mx, v);
    }
    const int sp = h * TT + t;
    s[((size_t)b * 2) * HW + sp] = sum * (1.f / (float)CC);
    s[((size_t)b * 2 + 1) * HW + sp] = mx;
}

// ---------------------------------------------------------------------------
// 7x7 conv on 2-ch pooled map + sigmoid (f32). Grid 1024x256.
// ---------------------------------------------------------------------------
__global__ __launch_bounds__(256) void spat_conv(const float* __restrict__ s,
                                                 const float* __restrict__ w,
                                                 float* __restrict__ a)
{
    __shared__ float wl[98];
    const int tid = threadIdx.x;
    if (tid < 98) wl[tid] = w[tid];
    __syncthreads();
    const int pix = blockIdx.x * 256 + tid;
    const int t = pix & 511, h = (pix >> 9) & 63, b = pix >> 15;
    float acc = 0.f;
#pragma unroll
    for (int ch = 0; ch < 2; ++ch) {
        const float* sp = s + ((size_t)b * 2 + ch) * HW;
#pragma unroll
        for (int di = 0; di < 7; ++di) {
            int hh = h + di - 3;
            if (hh < 0 || hh >= HH) continue;
#pragma unroll
            for (int dj = 0; dj < 7; ++dj) {
                int t2 = t + dj - 3;
                if (t2 < 0 || t2 >= TT) continue;
                acc += sp[hh * TT + t2] * wl[ch * 49 + di * 7 + dj];
            }
        }
    }
    a[pix] = sigf(acc);
}

// ---------------------------------------------------------------------------
// SSM scan (input-independent): writes states S[t][32] for both blocks.
// Grid: 2 blocks x 512 threads. (The sc = S@C GEMM is a separate, parallel
// kernel: doing it here put 32K LDS-read instrs on ONE CU = ~80us.)
// ---------------------------------------------------------------------------
__global__ __launch_bounds__(512) void scan_kernel(const float* __restrict__ A1,
                                                   const float* __restrict__ B1,
                                                   const float* __restrict__ A2,
                                                   const float* __restrict__ B2,
                                                   float* __restrict__ Sws)
{
    const float* A = blockIdx.x ? A2 : A1;
    const float* Bv = blockIdx.x ? B2 : B1;
    float* Sg = Sws + (size_t)blockIdx.x * (TT * 32);

    __shared__ float M[32][33];
    __shared__ float P[32][33];
    __shared__ float Q[32][33];
    __shared__ float L64[32];
    __shared__ float Eq[8][32];

    const int tid = threadIdx.x;
    const int wave = tid >> 6, lane = tid & 63;

    for (int idx = tid; idx < 1024; idx += 512) {
        int j = idx >> 5, i = idx & 31;
        float v = A[i * 32 + j];
        M[j][i] = v; P[j][i] = v;
    }
    __syncthreads();

    for (int sq = 0; sq < 6; ++sq) {
        for (int idx = tid; idx < 1024; idx += 512) {
            int r = idx >> 5, c2 = idx & 31;
            float acc = 0.f;
#pragma unroll
            for (int k = 0; k < 32; ++k) acc += P[r][k] * P[k][c2];
            Q[r][c2] = acc;
        }
        __syncthreads();
        for (int idx = tid; idx < 1024; idx += 512) {
            int r = idx >> 5, c2 = idx & 31;
            P[r][c2] = Q[r][c2];
        }
        __syncthreads();
    }

    if (wave == 0) {
        float bval = (lane < 32) ? Bv[lane] : 0.f;
        float z = 0.f;
        for (int r = 0; r < 64; ++r) {
            float zn = bval;
#pragma unroll
            for (int j = 0; j < 32; ++j) zn += __shfl(z, j, 64) * M[j][lane & 31];
            z = zn;
        }
        if (lane < 32) L64[lane] = z;
    }
    __syncthreads();

    if (wave == 0) {
        float e = 0.f;
        if (lane < 32) Eq[0][lane] = 0.f;
        for (int q = 1; q < 8; ++q) {
            float en = (lane < 32) ? L64[lane] : 0.f;
#pragma unroll
            for (int j = 0; j < 32; ++j) en += __shfl(e, j, 64) * P[j][lane & 31];
            e = en;
            if (lane < 32) Eq[q][lane] = e;
        }
    }
    __syncthreads();

    {
        float bval = (lane < 32) ? Bv[lane] : 0.f;
        float z = (lane < 32) ? Eq[wave][lane] : 0.f;
        for (int r = 0; r < 64; ++r) {
            float zn = bval;
#pragma unroll
            for (int j = 0; j < 32; ++j) zn += __shfl(z, j, 64) * M[j][lane & 31];
            z = zn;
            if (lane < 32) Sg[(wave * 64 + r) * 32 + lane] = z;
        }
    }
}

// ---------------------------------------------------------------------------
// sc[c][t] = S[t][:] . C[:][c] for both SSMs. Grid 32 blocks (ssm x 16 t-tiles
// of 32), 256 threads. float4 LDS reads, widely parallel (~4us total).
// ---------------------------------------------------------------------------
__global__ __launch_bounds__(256) void sc_gemm(const float* __restrict__ Sws,
                                               const float* __restrict__ C1,
                                               const float* __restrict__ C2,
                                               float* __restrict__ sc1,
                                               float* __restrict__ sc2)
{
    const int ssm = blockIdx.x >> 4, tt = blockIdx.x & 15;
    const int t0 = tt << 5;
    const float* Cm = ssm ? C2 : C1;
    float* sc = ssm ? sc2 : sc1;
    const float* S = Sws + (size_t)ssm * (TT * 32);

    __shared__ float Ssh[32][33];
    __shared__ float Csh[32][132];
    const int tid = threadIdx.x;

    for (int idx = tid; idx < 1024; idx += 256) {
        int t = idx >> 5, j = idx & 31;
        Ssh[t][j] = S[(t0 + t) * 32 + j];
    }
    for (int idx = tid; idx < 4096; idx += 256)
        Csh[idx >> 7][idx & 127] = Cm[idx];
    __syncthreads();

    const int t = tid & 31, cg = tid >> 5;
    const int c0 = cg * 16;
    float sreg[32];
#pragma unroll
    for (int j = 0; j < 32; ++j) sreg[j] = Ssh[t][j];
    float acc[16];
#pragma unroll
    for (int k = 0; k < 16; ++k) acc[k] = 0.f;
#pragma unroll
    for (int j = 0; j < 32; ++j) {
        float4 c4a = *(const float4*)&Csh[j][c0];
        float4 c4b = *(const float4*)&Csh[j][c0 + 4];
        float4 c4c = *(const float4*)&Csh[j][c0 + 8];
        float4 c4d = *(const float4*)&Csh[j][c0 + 12];
        const float s = sreg[j];
        acc[0] += s * c4a.x; acc[1] += s * c4a.y; acc[2] += s * c4a.z; acc[3] += s * c4a.w;
        acc[4] += s * c4b.x; acc[5] += s * c4b.y; acc[6] += s * c4b.z; acc[7] += s * c4b.w;
        acc[8] += s * c4c.x; acc[9] += s * c4c.y; acc[10] += s * c4c.z; acc[11] += s * c4c.w;
        acc[12] += s * c4d.x; acc[13] += s * c4d.y; acc[14] += s * c4d.z; acc[15] += s * c4d.w;
    }
#pragma unroll
    for (int k = 0; k < 16; ++k) sc[(c0 + k) * TT + t0 + t] = acc[k];
}

// ---------------------------------------------------------------------------
// Host-side launch
// ---------------------------------------------------------------------------
extern "C" void kernel_launch(void* const* d_in, const int* in_sizes, int n_in,
                              void* d_out, int out_size, void* d_ws, size_t ws_size,
                              hipStream_t stream)
{
    (void)in_sizes; (void)n_in; (void)out_size; (void)ws_size;

    auto pf = [&](int i) { return (const float*)d_in[i]; };

    const float* x = pf(0);

    const size_t NT = (size_t)BB * CC * HH * TT;      // 33554432
    unsigned short* B0 = (unsigned short*)d_ws;
    unsigned short* B1 = B0 + NT;
    unsigned short* B2 = B1 + NT;
    unsigned short* wbf = B2 + NT;                    // 8 x 16384 bf16
    float* sc1 = (float*)(wbf + 8 * 16384);
    float* sc2 = sc1 + CC * TT;
    float* Sws = sc2 + CC * TT;                       // 2*512*32
    float* pavg = Sws + 2 * TT * 32;
    float* pmax = pavg + BB * CC;
    float* achan = pmax + BB * CC;
    float* sspat = achan + BB * CC;                   // 8*2*32768
    float* aspat = sspat + (size_t)BB * 2 * HW;       // 262144
    float* OUT = (float*)d_out;

    const dim3 blk(256);
    const int PW_GRID = 4096;
    const int DW_GRID = 16384;
    const int PIX_GRID = NPIX / 256;                  // 1024
    const int D1_GRID = 16384;

    prep_weights<<<512, blk, 0, stream>>>(pf(1), pf(5), pf(8), pf(14),
                                          pf(22), pf(25), pf(31), pf(2), wbf);
    scan_kernel<<<2, 512, 0, stream>>>(pf(16), pf(17), pf(33), pf(34), Sws);
    sc_gemm<<<32, blk, 0, stream>>>(Sws, pf(18), pf(35), sc1, sc2);

    // stem: x(f32) -> B0 (bf16)
    pw_mfma<64, 0, false, false, true, false><<<PW_GRID, blk, 0, stream>>>(x, wbf + 0, nullptr, B0);

    auto run_block = [&](int pb, int wslot, const float* scp, bool flip) {
        // dw5x5 both branches: B0 -> B1(Da), B2(Db)
        if (flip)
            dw5x5_dual<true><<<DW_GRID, blk, 0, stream>>>(B0, pf(pb + 0), pf(pb + 3), B1, B2);
        else
            dw5x5_dual<false><<<DW_GRID, blk, 0, stream>>>(B0, pf(pb + 0), pf(pb + 3), B1, B2);
        // b1 = relu(bn(pw(Da))) -> B0 ; b2 = relu(bn(pw(Db))) -> B1
        pw_mfma<128, 1, false, true, false, false><<<PW_GRID, blk, 0, stream>>>(
            B1, wbf + (size_t)wslot * 16384, pf(pb + 2), B0);
        pw_mfma<128, 1, false, true, false, false><<<PW_GRID, blk, 0, stream>>>(
            B2, wbf + (size_t)(wslot + 1) * 16384, pf(pb + 5), B1);
        // channel attention on b1 (B0)
        chan_pool<<<BB * CC, blk, 0, stream>>>(B0, pavg, pmax);
        chan_mlp<<<1, blk, 0, stream>>>(pavg, pmax, pf(pb + 6), pf(pb + 7), achan);
        // cb chain: (b1^2*a) -> dw1x3 -> B2
        cb_dw1x3<<<D1_GRID, blk, 0, stream>>>(B0, achan, pf(pb + 9), B2);
        // spatial attention on b2 (B1) -> aspat (needed by fused kernel)
        spat_pool<<<PIX_GRID, blk, 0, stream>>>(B1, sspat);
        spat_conv<<<PIX_GRID, blk, 0, stream>>>(sspat, pf(pb + 8), aspat);
        // FUSED: pw(d1p)+bn+sigmoid + SSM/GELU + LN + *sigmoid(b2^2*aspat) -> B0
        pw_ssm<<<PW_GRID, blk, 0, stream>>>(B2, wbf + (size_t)(wslot + 2) * 16384,
                                            pf(pb + 11), B1, aspat, scp,
                                            pf(pb + 15), pf(pb + 16), B0);
    };

    // block 1 (weights slots 1,2,3), block 2 (slots 4,5,6; flipped reads)
    run_block(4, 1, sc1, false);
    run_block(21, 4, sc2, true);

    // final: relu(bn(pw(flip(B0), w_out))) -> d_out (f32)
    pw_mfma<128, 1, true, true, false, true><<<PW_GRID, blk, 0, stream>>>(
        B0, wbf + 7 * 16384, pf(3), OUT);
}